// Round 4
// baseline (2416.493 us; speedup 1.0000x reference)
//
#include <hip/hip_runtime.h>
#include <hip/hip_bf16.h>
#include <cstdint>
#include <cstddef>

#define HD 768   // H == H2
#define GD 2304  // 3*H2
#define DD 1536  // 2*H2

typedef __attribute__((ext_vector_type(8))) short bfrag8;  // 8 bf16 (4 VGPRs)
typedef __attribute__((ext_vector_type(4))) float f32x4;   // MFMA acc
typedef unsigned short ushort_t;

// ---------------- workspace layout ----------------
// region XP (fp32): live phase2(xp write)..phase3(gru read); overlaid in phase4
static constexpr size_t F_XP_TWF = 0;                      // 8192*2304
static constexpr size_t F_XP_TWB = 18874368;
static constexpr size_t F_XP_TPF = 37748736;               // 1024*2304
static constexpr size_t F_XP_TPB = 40108032;
// phase-4 overlay inside dead xp_twf region (first 18.87M floats):
static constexpr size_t F_TPWHI  = 0;                      // 1024*1536 ush = 786432 fl
static constexpr size_t F_TPWLO  = 786432;
static constexpr size_t F_WBLT_HI = 2000000;               // 1536*1536 ush = 1179648 fl
static constexpr size_t F_WBLT_LO = 3200000;
static constexpr size_t F_ATT    = 5000000;                // 64*16*128 fl
static constexpr size_t F_R      = 6000000;                // 1024*1536 fl
// region B (at F_B): phase1-2 = X/Wih bf16 splits (ushort offsets); phase3+ = TW/TP bf16 pairs
static constexpr size_t F_B      = 42467328;
static constexpr size_t U_XTW_HI  = 0;
static constexpr size_t U_XTW_LO  = 6291456;
static constexpr size_t U_XTP_HI  = 12582912;
static constexpr size_t U_XTP_LO  = 13369344;
static constexpr size_t U_WIHF_HI = 14155776;
static constexpr size_t U_WIHF_LO = 15925248;
static constexpr size_t U_WIHB_HI = 17694720;
static constexpr size_t U_WIHB_LO = 19464192;
static constexpr size_t U_TWHI   = 0;                      // 8192*1536 ush
static constexpr size_t U_TWLO   = 12582912;
static constexpr size_t U_TPHI   = 25165824;               // 1024*1536 ush
static constexpr size_t U_TPLO   = 26738688;               // ends 28311552 ush = 14155776 fl
// region Whh splits
static constexpr size_t F_WHH    = F_B + 14155776;         // 56623104
static constexpr size_t U_WHHF_HI = 0;
static constexpr size_t U_WHHF_LO = 1769472;
static constexpr size_t U_WHHB_HI = 3538944;
static constexpr size_t U_WHHB_LO = 5308416;
// H state: bf16 hi/lo ping-pong pairs
static constexpr size_t F_H      = F_WHH + 3538944;        // 60162048
static constexpr size_t U_HPAIR  = 442368;
static constexpr size_t U_HLO    = 221184;
// total = 60604416 floats

__device__ __forceinline__ float sigmoidf_(float x) { return 1.f / (1.f + expf(-x)); }
__device__ __forceinline__ ushort_t f2bf(float f) {
  unsigned int u = __builtin_bit_cast(unsigned int, f);
  unsigned int r = (u + 0x7fffu + ((u >> 16) & 1u)) >> 16;
  return (ushort_t)r;
}
__device__ __forceinline__ float bf2f(ushort_t h) {
  unsigned int u = ((unsigned int)h) << 16;
  return __builtin_bit_cast(float, u);
}
__device__ __forceinline__ void glds16(const ushort_t* src, ushort_t* ldsDst) {
  __builtin_amdgcn_global_load_lds((const void*)src, (void*)ldsDst, 16, 0, 0);
}

// ---------------- zero-init ----------------
__global__ void zero_kernel(float* __restrict__ p, int n) {
  int i = blockIdx.x * 256 + threadIdx.x;
  if (i < n) p[i] = 0.f;
}

// ---------------- gather + bf16 hi/lo split ----------------
__global__ __launch_bounds__(256) void gather_split_kernel(
    const int* __restrict__ ids, const float* __restrict__ emb,
    ushort_t* __restrict__ hi, ushort_t* __restrict__ lo, int total4)
{
  int i = blockIdx.x * 256 + threadIdx.x;
  if (i >= total4) return;
  int r = i / 192;
  int c = (i - r * 192) * 4;
  const float4 v = *reinterpret_cast<const float4*>(emb + (size_t)ids[r] * HD + c);
  float vv[4] = {v.x, v.y, v.z, v.w};
  ushort_t h[4], l[4];
#pragma unroll
  for (int e = 0; e < 4; ++e) { h[e] = f2bf(vv[e]); l[e] = f2bf(vv[e] - bf2f(h[e])); }
  size_t base = (size_t)i * 4;
  *reinterpret_cast<uint2*>(hi + base) = make_uint2((unsigned)h[0] | ((unsigned)h[1] << 16), (unsigned)h[2] | ((unsigned)h[3] << 16));
  *reinterpret_cast<uint2*>(lo + base) = make_uint2((unsigned)l[0] | ((unsigned)l[1] << 16), (unsigned)l[2] | ((unsigned)l[3] << 16));
}

__global__ __launch_bounds__(256) void split_w_kernel(
    const float* __restrict__ src, ushort_t* __restrict__ hi,
    ushort_t* __restrict__ lo, int total4)
{
  int i = blockIdx.x * 256 + threadIdx.x;
  if (i >= total4) return;
  const float4 v = *reinterpret_cast<const float4*>(src + (size_t)i * 4);
  float vv[4] = {v.x, v.y, v.z, v.w};
  ushort_t h[4], l[4];
#pragma unroll
  for (int e = 0; e < 4; ++e) { h[e] = f2bf(vv[e]); l[e] = f2bf(vv[e] - bf2f(h[e])); }
  size_t base = (size_t)i * 4;
  *reinterpret_cast<uint2*>(hi + base) = make_uint2((unsigned)h[0] | ((unsigned)h[1] << 16), (unsigned)h[2] | ((unsigned)h[3] << 16));
  *reinterpret_cast<uint2*>(lo + base) = make_uint2((unsigned)l[0] | ((unsigned)l[1] << 16), (unsigned)l[2] | ((unsigned)l[3] << 16));
}

// ---------------- W_bl transpose + split: WblT[d][k] = split(W_bl[k][d]) ----------------
__global__ __launch_bounds__(256) void transp_split_kernel(
    const float* __restrict__ src, ushort_t* __restrict__ hi, ushort_t* __restrict__ lo)
{
  __shared__ float t[32][33];
  const int bx = blockIdx.x, by = blockIdx.y, tid = threadIdx.x;
  const int r = tid >> 3, c4 = (tid & 7) * 4;
  const float4 v = *reinterpret_cast<const float4*>(src + (size_t)(by * 32 + r) * DD + bx * 32 + c4);
  t[r][c4 + 0] = v.x; t[r][c4 + 1] = v.y; t[r][c4 + 2] = v.z; t[r][c4 + 3] = v.w;
  __syncthreads();
  ushort_t h[4], l[4];
#pragma unroll
  for (int j = 0; j < 4; ++j) {
    float o = t[c4 + j][r];
    h[j] = f2bf(o); l[j] = f2bf(o - bf2f(h[j]));
  }
  size_t ob = (size_t)(bx * 32 + r) * DD + by * 32 + c4;
  *reinterpret_cast<uint2*>(hi + ob) = make_uint2((unsigned)h[0] | ((unsigned)h[1] << 16), (unsigned)h[2] | ((unsigned)h[3] << 16));
  *reinterpret_cast<uint2*>(lo + ob) = make_uint2((unsigned)l[0] | ((unsigned)l[1] << 16), (unsigned)l[2] | ((unsigned)l[3] << 16));
}

// ---------------- generalized bf16x3 MFMA GEMM ----------------
// out[M x N] = A[M x K] @ B[N x K]^T (+bias), C = Ahi Bhi + Alo Bhi + Ahi Blo
// BM=BN=128, BK=32, 256 thr = 4 waves (2x2), wave = 64x64 = 4x4 frags.
template<bool SPLIT_OUT>
__global__ __launch_bounds__(256, 3) void mfma_gemm_kernel(
    const ushort_t* __restrict__ Ahi, const ushort_t* __restrict__ Alo,
    const ushort_t* __restrict__ Bhi, const ushort_t* __restrict__ Blo,
    const float* __restrict__ bias, float* __restrict__ outF,
    ushort_t* __restrict__ outHi, ushort_t* __restrict__ outLo,
    const int K, const int N, const int mgc)
{
  __shared__ __align__(16) ushort_t sm[6][4096];
  const int b = blockIdx.x, nb = gridDim.x;
  const int id = (b & 7) * (nb >> 3) + (b >> 3);
  const int cg = id / mgc, mg = id % mgc;
  const size_t mBase = (size_t)mg * 128, nBase = (size_t)cg * 128;
  const int tid = threadIdx.x, lane = tid & 63, w = tid >> 6;
  const int wr = w >> 1, wc = w & 1;
  const int KB = K >> 5;

  const ushort_t* Ah = Ahi + mBase * K;
  const ushort_t* Al = Alo + mBase * K;
  const ushort_t* Bh = Bhi + nBase * K;
  const ushort_t* Bl = Blo + nBase * K;

  f32x4 acc[4][4];
#pragma unroll
  for (int i = 0; i < 4; ++i)
#pragma unroll
    for (int j = 0; j < 4; ++j) acc[i][j] = (f32x4){0.f, 0.f, 0.f, 0.f};

  auto stageF = [&](int buf, int koff) {
    ushort_t* Bt  = sm[buf * 3 + 0];
    ushort_t* At0 = sm[buf * 3 + 1];
    ushort_t* At1 = sm[buf * 3 + 2];
#pragma unroll
    for (int ii = 0; ii < 2; ++ii) {
      int i16 = w * 2 + ii;
      int row = i16 * 16 + (lane >> 2), c16 = lane & 3;
      size_t so = (size_t)row * K + (size_t)(koff + ((c16 ^ (row & 3)) << 3));
      glds16(Bh + so, Bt + i16 * 512);
      glds16(Ah + so, At0 + i16 * 512);
      glds16(Al + so, At1 + i16 * 512);
    }
  };
  auto stageP = [&](int buf, int koff) {
    ushort_t* Bt  = sm[buf * 3 + 0];
    ushort_t* At0 = sm[buf * 3 + 1];
#pragma unroll
    for (int ii = 0; ii < 2; ++ii) {
      int i16 = w * 2 + ii;
      int row = i16 * 16 + (lane >> 2), c16 = lane & 3;
      size_t so = (size_t)row * K + (size_t)(koff + ((c16 ^ (row & 3)) << 3));
      glds16(Bl + so, Bt + i16 * 512);
      glds16(Ah + so, At0 + i16 * 512);
    }
  };
  const int kch = (lane >> 4) << 4;

  auto compute = [&](int buf, bool both) {
    const char* Bt  = reinterpret_cast<const char*>(sm[buf * 3 + 0]);
    const char* At0 = reinterpret_cast<const char*>(sm[buf * 3 + 1]);
    const char* At1 = reinterpret_cast<const char*>(sm[buf * 3 + 2]);
    bfrag8 bF[4], aF[4];
#pragma unroll
    for (int j = 0; j < 4; ++j) {
      int row = wc * 64 + j * 16 + (lane & 15);
      bF[j] = *reinterpret_cast<const bfrag8*>(Bt + row * 64 + (kch ^ ((row & 3) << 4)));
    }
#pragma unroll
    for (int i = 0; i < 4; ++i) {
      int row = wr * 64 + i * 16 + (lane & 15);
      aF[i] = *reinterpret_cast<const bfrag8*>(At0 + row * 64 + (kch ^ ((row & 3) << 4)));
    }
#pragma unroll
    for (int i = 0; i < 4; ++i)
#pragma unroll
      for (int j = 0; j < 4; ++j)
        acc[i][j] = __builtin_amdgcn_mfma_f32_16x16x32_bf16(aF[i], bF[j], acc[i][j], 0, 0, 0);
    if (both) {
#pragma unroll
      for (int i = 0; i < 4; ++i) {
        int row = wr * 64 + i * 16 + (lane & 15);
        aF[i] = *reinterpret_cast<const bfrag8*>(At1 + row * 64 + (kch ^ ((row & 3) << 4)));
      }
#pragma unroll
      for (int i = 0; i < 4; ++i)
#pragma unroll
        for (int j = 0; j < 4; ++j)
          acc[i][j] = __builtin_amdgcn_mfma_f32_16x16x32_bf16(aF[i], bF[j], acc[i][j], 0, 0, 0);
    }
  };

  stageF(0, 0);
  __syncthreads();
  for (int kb = 0; kb < KB; ++kb) {
    if (kb < KB - 1) stageF((kb + 1) & 1, (kb + 1) * 32);
    else             stageP(0, 0);
    compute(kb & 1, true);
    __syncthreads();
  }
  for (int kb = 0; kb < KB; ++kb) {
    if (kb < KB - 1) stageP((kb + 1) & 1, (kb + 1) * 32);
    compute(kb & 1, false);
    __syncthreads();
  }

#pragma unroll
  for (int i = 0; i < 4; ++i)
#pragma unroll
    for (int j = 0; j < 4; ++j) {
      int col = (int)nBase + wc * 64 + j * 16 + (lane & 15);
#pragma unroll
      for (int p = 0; p < 4; ++p) {
        size_t row = mBase + wr * 64 + i * 16 + ((lane >> 4) << 2) + p;
        if constexpr (SPLIT_OUT) {
          float v = acc[i][j][p];
          ushort_t hh = f2bf(v);
          outHi[row * N + col] = hh;
          outLo[row * N + col] = f2bf(v - bf2f(hh));
        } else {
          outF[row * N + col] = acc[i][j][p] + bias[col];
        }
      }
    }
}

// ---------------- GRU step v2: A (H-state) persistent in LDS, BK=64 ----------------
// Rows 0..143 fwd (128 twf + 16 tpf), 144..287 bwd (128 twb + 16 tpb).
// grid 216 = 12 cg(64 cols) x 18 rg(16 rows); 4 waves, wave w owns cols [j0+16w,+16).
__global__ __launch_bounds__(256) void gru2_kernel(
    const ushort_t* __restrict__ WfHi, const ushort_t* __restrict__ WfLo,
    const ushort_t* __restrict__ WbHi, const ushort_t* __restrict__ WbLo,
    const float* __restrict__ bhhF, const float* __restrict__ bhhB,
    const float* __restrict__ xpTwf, const float* __restrict__ xpTwb,
    const float* __restrict__ xpTpf, const float* __restrict__ xpTpb,
    const ushort_t* __restrict__ Hc, ushort_t* __restrict__ Hn,
    ushort_t* __restrict__ TWhi, ushort_t* __restrict__ TWlo,
    ushort_t* __restrict__ TPhi, ushort_t* __restrict__ TPlo, const int s)
{
  __shared__ __align__(16) ushort_t Ah[12288];      // 24 frag-blocks (kb) x 512
  __shared__ __align__(16) ushort_t Al[12288];
  __shared__ __align__(16) ushort_t Bs[2][12288];   // 12 nf x 2 kb x 512 per buf
  const int b = blockIdx.x;
  const int id = (b & 7) * 27 + (b >> 3);
  const int cg = id / 18, rg = id % 18;
  const int rBase = rg * 16, j0 = cg * 64;
  const int dir = (rg >= 9);
  const ushort_t* Whi = dir ? WbHi : WfHi;
  const ushort_t* Wlo = dir ? WbLo : WfLo;
  const float* bhh = dir ? bhhB : bhhF;
  const int tid = threadIdx.x, lane = tid & 63, w = tid >> 6;
  const ushort_t* HcHi = Hc;
  const ushort_t* HcLo = Hc + U_HLO;

  // stage A (H hi+lo) once, frag-order: block kb covers k=[kb*32,+32)
  {
    const int r = lane & 15, kc = (lane >> 4) << 3;
    const ushort_t* sH = HcHi + (size_t)(rBase + r) * HD + kc;
    const ushort_t* sL = HcLo + (size_t)(rBase + r) * HD + kc;
#pragma unroll
    for (int ii = 0; ii < 6; ++ii) {
      int kb = w * 6 + ii;
      glds16(sH + kb * 32, Ah + kb * 512);
      glds16(sL + kb * 32, Al + kb * 512);
    }
  }
  auto stageB = [&](int buf, const ushort_t* Wsrc, int koff) {
    const int r = lane & 15, kc = (lane >> 4) << 3;
#pragma unroll
    for (int ii = 0; ii < 3; ++ii) {
      int nf = w * 3 + ii;                               // (gate = nf>>2, c16 = nf&3)
      size_t row = (size_t)(nf >> 2) * HD + j0 + ((nf & 3) << 4) + r;
#pragma unroll
      for (int kb = 0; kb < 2; ++kb)
        glds16(Wsrc + row * HD + koff + kb * 32 + kc, Bs[buf] + (nf * 2 + kb) * 512);
    }
  };
  stageB(0, Whi, 0);
  __syncthreads();

  f32x4 acc[3];
#pragma unroll
  for (int g = 0; g < 3; ++g) acc[g] = (f32x4){0.f, 0.f, 0.f, 0.f};

  for (int c = 0; c < 24; ++c) {
    if (c < 23) {
      int nc = c + 1;
      stageB(nc & 1, (nc < 12) ? Whi : Wlo, (nc % 12) * 64);
    }
    const char* Bb  = reinterpret_cast<const char*>(Bs[c & 1]);
    const char* AhC = reinterpret_cast<const char*>(Ah);
    const char* AlC = reinterpret_cast<const char*>(Al);
    const int cc = (c % 12) * 2;
#pragma unroll
    for (int kb = 0; kb < 2; ++kb) {
      bfrag8 aH = *reinterpret_cast<const bfrag8*>(AhC + (cc + kb) * 1024 + lane * 16);
      bfrag8 b0 = *reinterpret_cast<const bfrag8*>(Bb + ((0 * 4 + w) * 2 + kb) * 1024 + lane * 16);
      bfrag8 b1 = *reinterpret_cast<const bfrag8*>(Bb + ((1 * 4 + w) * 2 + kb) * 1024 + lane * 16);
      bfrag8 b2 = *reinterpret_cast<const bfrag8*>(Bb + ((2 * 4 + w) * 2 + kb) * 1024 + lane * 16);
      acc[0] = __builtin_amdgcn_mfma_f32_16x16x32_bf16(aH, b0, acc[0], 0, 0, 0);
      acc[1] = __builtin_amdgcn_mfma_f32_16x16x32_bf16(aH, b1, acc[1], 0, 0, 0);
      acc[2] = __builtin_amdgcn_mfma_f32_16x16x32_bf16(aH, b2, acc[2], 0, 0, 0);
      if (c < 12) {
        bfrag8 aL = *reinterpret_cast<const bfrag8*>(AlC + (cc + kb) * 1024 + lane * 16);
        acc[0] = __builtin_amdgcn_mfma_f32_16x16x32_bf16(aL, b0, acc[0], 0, 0, 0);
        acc[1] = __builtin_amdgcn_mfma_f32_16x16x32_bf16(aL, b1, acc[1], 0, 0, 0);
        acc[2] = __builtin_amdgcn_mfma_f32_16x16x32_bf16(aL, b2, acc[2], 0, 0, 0);
      }
    }
    __syncthreads();
  }

  // epilogue
  const int col = j0 + (w << 4) + (lane & 15);
  const int seg = (rg < 8) ? 0 : (rg == 8) ? 2 : (rg < 17) ? 1 : 3;
#pragma unroll
  for (int p = 0; p < 4; ++p) {
    const int gr = rBase + ((lane >> 4) << 2) + p;
    const float* xp; size_t orow; int ocol; bool isTW;
    if (seg == 0)      { int li = gr;                     xp = xpTwf + (size_t)(s * 128 + li) * GD;       orow = (size_t)s * 128 + li;        ocol = col;      isTW = true; }
    else if (seg == 1) { int li = gr - 144; int t = 63-s; xp = xpTwb + (size_t)(t * 128 + li) * GD;       orow = (size_t)t * 128 + li;        ocol = HD + col; isTW = true; }
    else if (seg == 2) { int li = gr - 128;               xp = xpTpf + (size_t)(s * 16 + li) * GD;        orow = (size_t)s * 16 + li;         ocol = col;      isTW = false; }
    else               { int li = gr - 272; int t = 63-s; xp = xpTpb + (size_t)(t * 16 + li) * GD;        orow = (size_t)t * 16 + li;         ocol = HD + col; isTW = false; }
    float rv = sigmoidf_(xp[col]          + acc[0][p] + bhh[col]);
    float zv = sigmoidf_(xp[HD + col]     + acc[1][p] + bhh[HD + col]);
    float nv = tanhf   (xp[2 * HD + col]  + rv * (acc[2][p] + bhh[2 * HD + col]));
    float hp = bf2f(HcHi[(size_t)gr * HD + col]) + bf2f(HcLo[(size_t)gr * HD + col]);
    float h = (1.f - zv) * nv + zv * hp;
    ushort_t hh = f2bf(h);
    ushort_t hl = f2bf(h - bf2f(hh));
    Hn[(size_t)gr * HD + col] = hh;
    Hn[U_HLO + (size_t)gr * HD + col] = hl;
    if (isTW) { TWhi[orow * DD + ocol] = hh; TWlo[orow * DD + ocol] = hl; }
    else      { TPhi[orow * DD + ocol] = hh; TPlo[orow * DD + ocol] = hl; }
  }
}

// ---------------- attn S + softmax per b (bf16x3 MFMA), writes att ----------------
// S[t][l] = sum_d TPW[b,t,d]*TW[b,l,d]; M=16(t), N=128(l), K=1536.
__global__ __launch_bounds__(256) void attn_s_kernel(
    const ushort_t* __restrict__ TPWhi, const ushort_t* __restrict__ TPWlo,
    const ushort_t* __restrict__ TWhi, const ushort_t* __restrict__ TWlo,
    float* __restrict__ attg)
{
  __shared__ __align__(16) ushort_t Ah[24576];     // 48 kb x 512
  __shared__ __align__(16) ushort_t Al[24576];
  __shared__ __align__(16) ushort_t Bs[2][4096];   // 8 nf x 512
  __shared__ float Sl[16][132];
  const int b = blockIdx.x;
  const int tid = threadIdx.x, lane = tid & 63, w = tid >> 6;
  const int r = lane & 15, kc = (lane >> 4) << 3;

  {
    const ushort_t* sH = TPWhi + ((size_t)b * 16 + r) * DD + kc;
    const ushort_t* sL = TPWlo + ((size_t)b * 16 + r) * DD + kc;
#pragma unroll
    for (int ii = 0; ii < 12; ++ii) {
      int kb = w * 12 + ii;
      glds16(sH + kb * 32, Ah + kb * 512);
      glds16(sL + kb * 32, Al + kb * 512);
    }
  }
  auto stageB = [&](int buf, const ushort_t* src, int koff) {
#pragma unroll
    for (int ii = 0; ii < 2; ++ii) {
      int nf = w * 2 + ii;
      glds16(src + ((size_t)b * 128 + nf * 16 + r) * DD + koff + kc, Bs[buf] + nf * 512);
    }
  };
  stageB(0, TWhi, 0);
  __syncthreads();

  f32x4 acc[2];
  acc[0] = (f32x4){0.f, 0.f, 0.f, 0.f};
  acc[1] = (f32x4){0.f, 0.f, 0.f, 0.f};
  for (int c = 0; c < 96; ++c) {
    if (c < 95) {
      int nc = c + 1;
      stageB(nc & 1, (nc < 48) ? TWhi : TWlo, (nc % 48) * 32);
    }
    const int kb = c % 48;
    bfrag8 aH = *reinterpret_cast<const bfrag8*>(reinterpret_cast<const char*>(Ah) + kb * 1024 + lane * 16);
    bfrag8 b0 = *reinterpret_cast<const bfrag8*>(reinterpret_cast<const char*>(Bs[c & 1]) + (w * 2 + 0) * 1024 + lane * 16);
    bfrag8 b1 = *reinterpret_cast<const bfrag8*>(reinterpret_cast<const char*>(Bs[c & 1]) + (w * 2 + 1) * 1024 + lane * 16);
    acc[0] = __builtin_amdgcn_mfma_f32_16x16x32_bf16(aH, b0, acc[0], 0, 0, 0);
    acc[1] = __builtin_amdgcn_mfma_f32_16x16x32_bf16(aH, b1, acc[1], 0, 0, 0);
    if (c < 48) {
      bfrag8 aL = *reinterpret_cast<const bfrag8*>(reinterpret_cast<const char*>(Al) + kb * 1024 + lane * 16);
      acc[0] = __builtin_amdgcn_mfma_f32_16x16x32_bf16(aL, b0, acc[0], 0, 0, 0);
      acc[1] = __builtin_amdgcn_mfma_f32_16x16x32_bf16(aL, b1, acc[1], 0, 0, 0);
    }
    __syncthreads();
  }

#pragma unroll
  for (int nfl = 0; nfl < 2; ++nfl) {
    int l = (w * 2 + nfl) * 16 + (lane & 15);
#pragma unroll
    for (int p = 0; p < 4; ++p) Sl[(lane >> 4) * 4 + p][l] = acc[nfl][p];
  }
  __syncthreads();

  // softmax: 16 threads per t-row
  const int t = tid >> 4, j = tid & 15;
  float4 v0 = *reinterpret_cast<const float4*>(&Sl[t][j * 8]);
  float4 v1 = *reinterpret_cast<const float4*>(&Sl[t][j * 8 + 4]);
  float m = fmaxf(fmaxf(fmaxf(v0.x, v0.y), fmaxf(v0.z, v0.w)),
                  fmaxf(fmaxf(v1.x, v1.y), fmaxf(v1.z, v1.w)));
#pragma unroll
  for (int mk = 1; mk < 16; mk <<= 1) m = fmaxf(m, __shfl_xor(m, mk));
  float e[8];
  e[0] = expf(v0.x - m); e[1] = expf(v0.y - m); e[2] = expf(v0.z - m); e[3] = expf(v0.w - m);
  e[4] = expf(v1.x - m); e[5] = expf(v1.y - m); e[6] = expf(v1.z - m); e[7] = expf(v1.w - m);
  float ssum = e[0] + e[1] + e[2] + e[3] + e[4] + e[5] + e[6] + e[7];
#pragma unroll
  for (int mk = 1; mk < 16; mk <<= 1) ssum += __shfl_xor(ssum, mk);
  const float inv = 1.f / ssum;
  float* po = attg + (size_t)b * 2048 + t * 128 + j * 8;
  *reinterpret_cast<float4*>(po)     = make_float4(e[0] * inv, e[1] * inv, e[2] * inv, e[3] * inv);
  *reinterpret_cast<float4*>(po + 4) = make_float4(e[4] * inv, e[5] * inv, e[6] * inv, e[7] * inv);
}

// ---------------- r2: r[b,t,d] = sum_l att[b,t,l] * TW[b,l,d] ----------------
__global__ __launch_bounds__(256) void r2_kernel(
    const float* __restrict__ attg, const ushort_t* __restrict__ TWhi,
    const ushort_t* __restrict__ TWlo, float* __restrict__ Rr)
{
  __shared__ float al[2048];
  const int b = blockIdx.y;
  const int d = blockIdx.x * 256 + threadIdx.x;
  for (int i = threadIdx.x; i < 2048; i += 256) al[i] = attg[(size_t)b * 2048 + i];
  __syncthreads();
  float racc[16];
#pragma unroll
  for (int t = 0; t < 16; ++t) racc[t] = 0.f;
  for (int l = 0; l < 128; ++l) {
    size_t o = ((size_t)b * 128 + l) * DD + d;
    float tw = bf2f(TWhi[o]) + bf2f(TWlo[o]);
#pragma unroll
    for (int t = 0; t < 16; ++t) racc[t] += al[t * 128 + l] * tw;
  }
#pragma unroll
  for (int t = 0; t < 16; ++t) Rr[((size_t)b * 16 + t) * DD + d] = racc[t];
}

// ---------------- R assembly + head ----------------
__global__ __launch_bounds__(256) void final_kernel(
    const float* __restrict__ Rr, const float* __restrict__ beta,
    const float* __restrict__ detW, const float* __restrict__ detb,
    float* __restrict__ dout)
{
  __shared__ float bet[16];
  __shared__ float red0[256], red1[256];
  const int b = blockIdx.x, tid = threadIdx.x;
  if (tid < 16) bet[tid] = beta[tid];
  __syncthreads();
  const float* rb = Rr + (size_t)b * 16 * DD;
  float* Rout = dout + 128 + (size_t)b * 3072;
  float p0 = 0.f, p1 = 0.f;
  for (int d = tid; d < 3072; d += 256) {
    float v;
    if (d < DD) {
      v = rb[15 * DD + d];
    } else {
      float sum = 0.f;
#pragma unroll
      for (int tt = 0; tt < 15; ++tt) sum += bet[tt] * rb[(size_t)tt * DD + (d - DD)];
      v = sum;
    }
    Rout[d] = v;
    p0 += v * detW[d];
    p1 += v * detW[3072 + d];
  }
  red0[tid] = p0; red1[tid] = p1;
  __syncthreads();
  for (int off = 128; off > 0; off >>= 1) {
    if (tid < off) { red0[tid] += red0[tid + off]; red1[tid] += red1[tid + off]; }
    __syncthreads();
  }
  if (tid == 0) {
    dout[b * 2 + 0] = red0[0] + detb[0];
    dout[b * 2 + 1] = red1[0] + detb[1];
  }
}

// ---------------- launch ----------------
extern "C" void kernel_launch(void* const* d_in, const int* in_sizes, int n_in,
                              void* d_out, int out_size, void* d_ws, size_t ws_size,
                              hipStream_t stream)
{
  (void)in_sizes; (void)n_in; (void)out_size; (void)ws_size;
  const int*   tweet = (const int*)  d_in[0];
  const int*   topic = (const int*)  d_in[1];
  const float* beta  = (const float*)d_in[2];
  const float* emb   = (const float*)d_in[3];
  const float* Wih_f = (const float*)d_in[4];
  const float* Whh_f = (const float*)d_in[5];
  const float* bih_f = (const float*)d_in[6];
  const float* bhh_f = (const float*)d_in[7];
  const float* Wih_b = (const float*)d_in[8];
  const float* Whh_b = (const float*)d_in[9];
  const float* bih_b = (const float*)d_in[10];
  const float* bhh_b = (const float*)d_in[11];
  const float* W_bl  = (const float*)d_in[12];
  const float* det_W = (const float*)d_in[13];
  const float* det_b = (const float*)d_in[14];

  float* ws = (float*)d_ws;
  float* xp_twf = ws + F_XP_TWF;
  float* xp_twb = ws + F_XP_TWB;
  float* xp_tpf = ws + F_XP_TPF;
  float* xp_tpb = ws + F_XP_TPB;
  float* attg   = ws + F_ATT;
  float* Rr     = ws + F_R;
  ushort_t* TPWhi = (ushort_t*)(ws + F_TPWHI);
  ushort_t* TPWlo = (ushort_t*)(ws + F_TPWLO);
  ushort_t* WblTh = (ushort_t*)(ws + F_WBLT_HI);
  ushort_t* WblTl = (ushort_t*)(ws + F_WBLT_LO);
  ushort_t* uB    = (ushort_t*)(ws + F_B);
  ushort_t* uWhh  = (ushort_t*)(ws + F_WHH);
  ushort_t* uH    = (ushort_t*)(ws + F_H);

  // phase 0: zero H pair 0
  zero_kernel<<<dim3(864), dim3(256), 0, stream>>>(ws + F_H, 221184);

  // phase 1: bf16 splits
  gather_split_kernel<<<dim3(6144), dim3(256), 0, stream>>>(tweet, emb, uB + U_XTW_HI, uB + U_XTW_LO, 1572864);
  gather_split_kernel<<<dim3(768),  dim3(256), 0, stream>>>(topic, emb, uB + U_XTP_HI, uB + U_XTP_LO, 196608);
  split_w_kernel<<<dim3(1728), dim3(256), 0, stream>>>(Wih_f, uB + U_WIHF_HI, uB + U_WIHF_LO, 442368);
  split_w_kernel<<<dim3(1728), dim3(256), 0, stream>>>(Wih_b, uB + U_WIHB_HI, uB + U_WIHB_LO, 442368);
  split_w_kernel<<<dim3(1728), dim3(256), 0, stream>>>(Whh_f, uWhh + U_WHHF_HI, uWhh + U_WHHF_LO, 442368);
  split_w_kernel<<<dim3(1728), dim3(256), 0, stream>>>(Whh_b, uWhh + U_WHHB_HI, uWhh + U_WHHB_LO, 442368);

  // phase 2: xp GEMMs
  mfma_gemm_kernel<false><<<dim3(1152), dim3(256), 0, stream>>>(uB + U_XTW_HI, uB + U_XTW_LO, uB + U_WIHF_HI, uB + U_WIHF_LO, bih_f, xp_twf, nullptr, nullptr, HD, GD, 64);
  mfma_gemm_kernel<false><<<dim3(1152), dim3(256), 0, stream>>>(uB + U_XTW_HI, uB + U_XTW_LO, uB + U_WIHB_HI, uB + U_WIHB_LO, bih_b, xp_twb, nullptr, nullptr, HD, GD, 64);
  mfma_gemm_kernel<false><<<dim3(144),  dim3(256), 0, stream>>>(uB + U_XTP_HI, uB + U_XTP_LO, uB + U_WIHF_HI, uB + U_WIHF_LO, bih_f, xp_tpf, nullptr, nullptr, HD, GD, 8);
  mfma_gemm_kernel<false><<<dim3(144),  dim3(256), 0, stream>>>(uB + U_XTP_HI, uB + U_XTP_LO, uB + U_WIHB_HI, uB + U_WIHB_LO, bih_b, xp_tpb, nullptr, nullptr, HD, GD, 8);

  // phase 3: 64 GRU steps
  for (int s = 0; s < 64; ++s) {
    const ushort_t* Hc = uH + (size_t)(s & 1) * U_HPAIR;
    ushort_t*       Hn = uH + (size_t)((s & 1) ^ 1) * U_HPAIR;
    gru2_kernel<<<dim3(216), dim3(256), 0, stream>>>(
        uWhh + U_WHHF_HI, uWhh + U_WHHF_LO, uWhh + U_WHHB_HI, uWhh + U_WHHB_LO,
        bhh_f, bhh_b, xp_twf, xp_twb, xp_tpf, xp_tpb, Hc, Hn,
        uB + U_TWHI, uB + U_TWLO, uB + U_TPHI, uB + U_TPLO, s);
  }

  // phase 4: attention + head
  transp_split_kernel<<<dim3(48, 48), dim3(256), 0, stream>>>(W_bl, WblTh, WblTl);
  mfma_gemm_kernel<true><<<dim3(96), dim3(256), 0, stream>>>(uB + U_TPHI, uB + U_TPLO, WblTh, WblTl, nullptr, nullptr, TPWhi, TPWlo, DD, DD, 8);
  attn_s_kernel<<<dim3(64), dim3(256), 0, stream>>>(TPWhi, TPWlo, uB + U_TWHI, uB + U_TWLO, attg);
  r2_kernel<<<dim3(6, 64), dim3(256), 0, stream>>>(attg, uB + U_TWHI, uB + U_TWLO, Rr);
  final_kernel<<<dim3(64), dim3(256), 0, stream>>>(Rr, beta, det_W, det_b, (float*)d_out);
}

// Round 5
// 1878.902 us; speedup vs baseline: 1.2861x; 1.2861x over previous
//
#include <hip/hip_runtime.h>
#include <hip/hip_bf16.h>
#include <cstdint>
#include <cstddef>

#define HD 768   // H == H2
#define GD 2304  // 3*H2
#define DD 1536  // 2*H2

typedef __attribute__((ext_vector_type(8))) short bfrag8;  // 8 bf16 (4 VGPRs)
typedef __attribute__((ext_vector_type(4))) float f32x4;   // MFMA acc
typedef unsigned short ushort_t;

// ---------------- workspace layout ----------------
static constexpr size_t F_XP_TWF = 0;                      // 8192*2304
static constexpr size_t F_XP_TWB = 18874368;
static constexpr size_t F_XP_TPF = 37748736;               // 1024*2304
static constexpr size_t F_XP_TPB = 40108032;
// phase-4 overlay inside dead xp_twf region:
static constexpr size_t F_TPWHI  = 0;
static constexpr size_t F_TPWLO  = 786432;
static constexpr size_t F_WBLT_HI = 2000000;
static constexpr size_t F_WBLT_LO = 3200000;
static constexpr size_t F_ATT    = 5000000;
static constexpr size_t F_R      = 6000000;
// region B: phase1-2 = X/Wih splits; phase3+ = TW/TP bf16 pairs
static constexpr size_t F_B      = 42467328;
static constexpr size_t U_XTW_HI  = 0;
static constexpr size_t U_XTW_LO  = 6291456;
static constexpr size_t U_XTP_HI  = 12582912;
static constexpr size_t U_XTP_LO  = 13369344;
static constexpr size_t U_WIHF_HI = 14155776;
static constexpr size_t U_WIHF_LO = 15925248;
static constexpr size_t U_WIHB_HI = 17694720;
static constexpr size_t U_WIHB_LO = 19464192;
static constexpr size_t U_TWHI   = 0;
static constexpr size_t U_TWLO   = 12582912;
static constexpr size_t U_TPHI   = 25165824;
static constexpr size_t U_TPLO   = 26738688;
// region Whh splits
static constexpr size_t F_WHH    = F_B + 14155776;
static constexpr size_t U_WHHF_HI = 0;
static constexpr size_t U_WHHF_LO = 1769472;
static constexpr size_t U_WHHB_HI = 3538944;
static constexpr size_t U_WHHB_LO = 5308416;
// H state: bf16 hi/lo ping-pong pairs
static constexpr size_t F_H      = F_WHH + 3538944;
static constexpr size_t U_HPAIR  = 442368;
static constexpr size_t U_HLO    = 221184;

__device__ __forceinline__ float sigmoidf_(float x) { return 1.f / (1.f + expf(-x)); }
__device__ __forceinline__ ushort_t f2bf(float f) {
  unsigned int u = __builtin_bit_cast(unsigned int, f);
  unsigned int r = (u + 0x7fffu + ((u >> 16) & 1u)) >> 16;
  return (ushort_t)r;
}
__device__ __forceinline__ float bf2f(ushort_t h) {
  unsigned int u = ((unsigned int)h) << 16;
  return __builtin_bit_cast(float, u);
}
__device__ __forceinline__ void glds16(const ushort_t* src, ushort_t* ldsDst) {
  __builtin_amdgcn_global_load_lds((const void*)src, (void*)ldsDst, 16, 0, 0);
}

// ---------------- zero-init ----------------
__global__ void zero_kernel(float* __restrict__ p, int n) {
  int i = blockIdx.x * 256 + threadIdx.x;
  if (i < n) p[i] = 0.f;
}

// ---------------- gather + bf16 hi/lo split ----------------
__global__ __launch_bounds__(256) void gather_split_kernel(
    const int* __restrict__ ids, const float* __restrict__ emb,
    ushort_t* __restrict__ hi, ushort_t* __restrict__ lo, int total4)
{
  int i = blockIdx.x * 256 + threadIdx.x;
  if (i >= total4) return;
  int r = i / 192;
  int c = (i - r * 192) * 4;
  const float4 v = *reinterpret_cast<const float4*>(emb + (size_t)ids[r] * HD + c);
  float vv[4] = {v.x, v.y, v.z, v.w};
  ushort_t h[4], l[4];
#pragma unroll
  for (int e = 0; e < 4; ++e) { h[e] = f2bf(vv[e]); l[e] = f2bf(vv[e] - bf2f(h[e])); }
  size_t base = (size_t)i * 4;
  *reinterpret_cast<uint2*>(hi + base) = make_uint2((unsigned)h[0] | ((unsigned)h[1] << 16), (unsigned)h[2] | ((unsigned)h[3] << 16));
  *reinterpret_cast<uint2*>(lo + base) = make_uint2((unsigned)l[0] | ((unsigned)l[1] << 16), (unsigned)l[2] | ((unsigned)l[3] << 16));
}

__global__ __launch_bounds__(256) void split_w_kernel(
    const float* __restrict__ src, ushort_t* __restrict__ hi,
    ushort_t* __restrict__ lo, int total4)
{
  int i = blockIdx.x * 256 + threadIdx.x;
  if (i >= total4) return;
  const float4 v = *reinterpret_cast<const float4*>(src + (size_t)i * 4);
  float vv[4] = {v.x, v.y, v.z, v.w};
  ushort_t h[4], l[4];
#pragma unroll
  for (int e = 0; e < 4; ++e) { h[e] = f2bf(vv[e]); l[e] = f2bf(vv[e] - bf2f(h[e])); }
  size_t base = (size_t)i * 4;
  *reinterpret_cast<uint2*>(hi + base) = make_uint2((unsigned)h[0] | ((unsigned)h[1] << 16), (unsigned)h[2] | ((unsigned)h[3] << 16));
  *reinterpret_cast<uint2*>(lo + base) = make_uint2((unsigned)l[0] | ((unsigned)l[1] << 16), (unsigned)l[2] | ((unsigned)l[3] << 16));
}

// ---------------- W_bl transpose + split ----------------
__global__ __launch_bounds__(256) void transp_split_kernel(
    const float* __restrict__ src, ushort_t* __restrict__ hi, ushort_t* __restrict__ lo)
{
  __shared__ float t[32][33];
  const int bx = blockIdx.x, by = blockIdx.y, tid = threadIdx.x;
  const int r = tid >> 3, c4 = (tid & 7) * 4;
  const float4 v = *reinterpret_cast<const float4*>(src + (size_t)(by * 32 + r) * DD + bx * 32 + c4);
  t[r][c4 + 0] = v.x; t[r][c4 + 1] = v.y; t[r][c4 + 2] = v.z; t[r][c4 + 3] = v.w;
  __syncthreads();
  ushort_t h[4], l[4];
#pragma unroll
  for (int j = 0; j < 4; ++j) {
    float o = t[c4 + j][r];
    h[j] = f2bf(o); l[j] = f2bf(o - bf2f(h[j]));
  }
  size_t ob = (size_t)(bx * 32 + r) * DD + by * 32 + c4;
  *reinterpret_cast<uint2*>(hi + ob) = make_uint2((unsigned)h[0] | ((unsigned)h[1] << 16), (unsigned)h[2] | ((unsigned)h[3] << 16));
  *reinterpret_cast<uint2*>(lo + ob) = make_uint2((unsigned)l[0] | ((unsigned)l[1] << 16), (unsigned)l[2] | ((unsigned)l[3] << 16));
}

// ---------------- generalized bf16x3 MFMA GEMM (unchanged from round 4) ----------------
template<bool SPLIT_OUT>
__global__ __launch_bounds__(256, 3) void mfma_gemm_kernel(
    const ushort_t* __restrict__ Ahi, const ushort_t* __restrict__ Alo,
    const ushort_t* __restrict__ Bhi, const ushort_t* __restrict__ Blo,
    const float* __restrict__ bias, float* __restrict__ outF,
    ushort_t* __restrict__ outHi, ushort_t* __restrict__ outLo,
    const int K, const int N, const int mgc)
{
  __shared__ __align__(16) ushort_t sm[6][4096];
  const int b = blockIdx.x, nb = gridDim.x;
  const int id = (b & 7) * (nb >> 3) + (b >> 3);
  const int cg = id / mgc, mg = id % mgc;
  const size_t mBase = (size_t)mg * 128, nBase = (size_t)cg * 128;
  const int tid = threadIdx.x, lane = tid & 63, w = tid >> 6;
  const int wr = w >> 1, wc = w & 1;
  const int KB = K >> 5;

  const ushort_t* Ah = Ahi + mBase * K;
  const ushort_t* Al = Alo + mBase * K;
  const ushort_t* Bh = Bhi + nBase * K;
  const ushort_t* Bl = Blo + nBase * K;

  f32x4 acc[4][4];
#pragma unroll
  for (int i = 0; i < 4; ++i)
#pragma unroll
    for (int j = 0; j < 4; ++j) acc[i][j] = (f32x4){0.f, 0.f, 0.f, 0.f};

  auto stageF = [&](int buf, int koff) {
    ushort_t* Bt  = sm[buf * 3 + 0];
    ushort_t* At0 = sm[buf * 3 + 1];
    ushort_t* At1 = sm[buf * 3 + 2];
#pragma unroll
    for (int ii = 0; ii < 2; ++ii) {
      int i16 = w * 2 + ii;
      int row = i16 * 16 + (lane >> 2), c16 = lane & 3;
      size_t so = (size_t)row * K + (size_t)(koff + ((c16 ^ (row & 3)) << 3));
      glds16(Bh + so, Bt + i16 * 512);
      glds16(Ah + so, At0 + i16 * 512);
      glds16(Al + so, At1 + i16 * 512);
    }
  };
  auto stageP = [&](int buf, int koff) {
    ushort_t* Bt  = sm[buf * 3 + 0];
    ushort_t* At0 = sm[buf * 3 + 1];
#pragma unroll
    for (int ii = 0; ii < 2; ++ii) {
      int i16 = w * 2 + ii;
      int row = i16 * 16 + (lane >> 2), c16 = lane & 3;
      size_t so = (size_t)row * K + (size_t)(koff + ((c16 ^ (row & 3)) << 3));
      glds16(Bl + so, Bt + i16 * 512);
      glds16(Ah + so, At0 + i16 * 512);
    }
  };
  const int kch = (lane >> 4) << 4;

  auto compute = [&](int buf, bool both) {
    const char* Bt  = reinterpret_cast<const char*>(sm[buf * 3 + 0]);
    const char* At0 = reinterpret_cast<const char*>(sm[buf * 3 + 1]);
    const char* At1 = reinterpret_cast<const char*>(sm[buf * 3 + 2]);
    bfrag8 bF[4], aF[4];
#pragma unroll
    for (int j = 0; j < 4; ++j) {
      int row = wc * 64 + j * 16 + (lane & 15);
      bF[j] = *reinterpret_cast<const bfrag8*>(Bt + row * 64 + (kch ^ ((row & 3) << 4)));
    }
#pragma unroll
    for (int i = 0; i < 4; ++i) {
      int row = wr * 64 + i * 16 + (lane & 15);
      aF[i] = *reinterpret_cast<const bfrag8*>(At0 + row * 64 + (kch ^ ((row & 3) << 4)));
    }
#pragma unroll
    for (int i = 0; i < 4; ++i)
#pragma unroll
      for (int j = 0; j < 4; ++j)
        acc[i][j] = __builtin_amdgcn_mfma_f32_16x16x32_bf16(aF[i], bF[j], acc[i][j], 0, 0, 0);
    if (both) {
#pragma unroll
      for (int i = 0; i < 4; ++i) {
        int row = wr * 64 + i * 16 + (lane & 15);
        aF[i] = *reinterpret_cast<const bfrag8*>(At1 + row * 64 + (kch ^ ((row & 3) << 4)));
      }
#pragma unroll
      for (int i = 0; i < 4; ++i)
#pragma unroll
        for (int j = 0; j < 4; ++j)
          acc[i][j] = __builtin_amdgcn_mfma_f32_16x16x32_bf16(aF[i], bF[j], acc[i][j], 0, 0, 0);
    }
  };

  stageF(0, 0);
  __syncthreads();
  for (int kb = 0; kb < KB; ++kb) {
    if (kb < KB - 1) stageF((kb + 1) & 1, (kb + 1) * 32);
    else             stageP(0, 0);
    compute(kb & 1, true);
    __syncthreads();
  }
  for (int kb = 0; kb < KB; ++kb) {
    if (kb < KB - 1) stageP((kb + 1) & 1, (kb + 1) * 32);
    compute(kb & 1, false);
    __syncthreads();
  }

#pragma unroll
  for (int i = 0; i < 4; ++i)
#pragma unroll
    for (int j = 0; j < 4; ++j) {
      int col = (int)nBase + wc * 64 + j * 16 + (lane & 15);
#pragma unroll
      for (int p = 0; p < 4; ++p) {
        size_t row = mBase + wr * 64 + i * 16 + ((lane >> 4) << 2) + p;
        if constexpr (SPLIT_OUT) {
          float v = acc[i][j][p];
          ushort_t hh = f2bf(v);
          outHi[row * N + col] = hh;
          outLo[row * N + col] = f2bf(v - bf2f(hh));
        } else {
          outF[row * N + col] = acc[i][j][p] + bias[col];
        }
      }
    }
}

// ---------------- GRU step v3: XCD-pinned L2-resident Whh slices ----------------
// Grid 240 (= 8 XCD x 30). Per XCD: 24 tweet blocks (6 slices x 4 rg, M=32) +
// 6 topic blocks (same 6 slices, M=16). slice = (cg of 32 cols, dir). N = 96
// gate-rows (3 gates x 32 cols). Whh slice hi+lo = 294 KB; 6 slices + H state
// = ~2.7 MB per XCD -> L2-resident, persists across the 64 step launches.
// LDS: 16 frag-slots (1KB) x dbuf = 32 KB. Waves: (mf = w&1, ch = w>>1);
// lane's acc[0..2][p] = r/z/n pre-activations of one (row, col).
__global__ __launch_bounds__(256) void gru3_kernel(
    const ushort_t* __restrict__ WfHi, const ushort_t* __restrict__ WfLo,
    const ushort_t* __restrict__ WbHi, const ushort_t* __restrict__ WbLo,
    const float* __restrict__ bhhF, const float* __restrict__ bhhB,
    const float* __restrict__ xpTwf, const float* __restrict__ xpTwb,
    const float* __restrict__ xpTpf, const float* __restrict__ xpTpb,
    const ushort_t* __restrict__ Hc, ushort_t* __restrict__ Hn,
    ushort_t* __restrict__ TWhi, ushort_t* __restrict__ TWlo,
    ushort_t* __restrict__ TPhi, ushort_t* __restrict__ TPlo, const int s)
{
  __shared__ __align__(16) ushort_t sm[2][16][512];
  const int bid = blockIdx.x;
  const int xcd = bid & 7, kk = bid >> 3;          // kk 0..29
  const bool isTweet = (kk < 24);
  const int sl = isTweet ? (kk >> 2) : (kk - 24);  // 0..5
  const int rg = isTweet ? (kk & 3) : 0;
  const int slice = xcd * 6 + sl;                  // 0..47
  const int cg = slice >> 1, dir = slice & 1;
  const int j0 = cg * 32;
  const int Mfrags = isTweet ? 2 : 1;
  const int baseR = dir * 144 + (isTweet ? rg * 32 : 128);
  const ushort_t* __restrict__ Whi = dir ? WbHi : WfHi;
  const ushort_t* __restrict__ Wlo = dir ? WbLo : WfLo;
  const float* __restrict__ bhh = dir ? bhhB : bhhF;
  const int tid = threadIdx.x, lane = tid & 63, w = tid >> 6;
  const ushort_t* HcHi = Hc;
  const ushort_t* HcLo = Hc + U_HLO;

  const int mf = isTweet ? (w & 1) : 0;
  const int ch = isTweet ? (w >> 1) : w;           // topic: waves 0,1 -> ch 0,1
  const bool doCompute = isTweet || (w < 2);

  // stage: wave w stages slots 4w..4w+3 of chunk kb
  auto stage = [&](int buf, int kb) {
    const int r16 = lane & 15, k8 = (lane >> 4) << 3;
#pragma unroll
    for (int i = 0; i < 4; ++i) {
      const int slot = w * 4 + i;
      if (slot < 4) {
        const int m = slot >> 1, p = slot & 1;
        if (m < Mfrags) {
          const ushort_t* src = (p ? HcLo : HcHi) +
              (size_t)(baseR + m * 16 + r16) * HD + kb * 32 + k8;
          glds16(src, &sm[buf][slot][0]);
        }
      } else {
        const int idx = slot - 4;                  // (g*2+ch)*2+p
        const int p = idx & 1, c2 = (idx >> 1) & 1, g = idx >> 2;
        const ushort_t* W = p ? Wlo : Whi;
        const ushort_t* src = W +
            (size_t)(g * HD + j0 + c2 * 16 + r16) * HD + kb * 32 + k8;
        glds16(src, &sm[buf][slot][0]);
      }
    }
  };

  f32x4 acc[3];
#pragma unroll
  for (int g = 0; g < 3; ++g) acc[g] = (f32x4){0.f, 0.f, 0.f, 0.f};

  auto computeT = [&](int buf) {
    if (!doCompute) return;
    const char* base = reinterpret_cast<const char*>(&sm[buf][0][0]);
    const int aoff = mf * 2;
    bfrag8 Ah = *reinterpret_cast<const bfrag8*>(base + (aoff + 0) * 1024 + lane * 16);
    bfrag8 Al = *reinterpret_cast<const bfrag8*>(base + (aoff + 1) * 1024 + lane * 16);
#pragma unroll
    for (int g = 0; g < 3; ++g) {
      const int bidx = 4 + (g * 2 + ch) * 2;
      bfrag8 Bh = *reinterpret_cast<const bfrag8*>(base + (bidx + 0) * 1024 + lane * 16);
      bfrag8 Bl = *reinterpret_cast<const bfrag8*>(base + (bidx + 1) * 1024 + lane * 16);
      acc[g] = __builtin_amdgcn_mfma_f32_16x16x32_bf16(Ah, Bh, acc[g], 0, 0, 0);
      acc[g] = __builtin_amdgcn_mfma_f32_16x16x32_bf16(Al, Bh, acc[g], 0, 0, 0);
      acc[g] = __builtin_amdgcn_mfma_f32_16x16x32_bf16(Ah, Bl, acc[g], 0, 0, 0);
    }
  };

  stage(0, 0);
  __syncthreads();
  for (int kb = 0; kb < 24; ++kb) {
    if (kb < 23) stage((kb + 1) & 1, kb + 1);
    computeT(kb & 1);
    __syncthreads();
  }

  // epilogue
  if (doCompute) {
    const int colG = j0 + ch * 16 + (lane & 15);   // 0..767
#pragma unroll
    for (int p = 0; p < 4; ++p) {
      const int lr = mf * 16 + ((lane >> 4) << 2) + p;
      const int gr = baseR + lr;
      const float* xp; size_t orow; int ocol; bool isTW;
      if (isTweet) {
        const int li = rg * 32 + lr;
        if (dir == 0) { xp = xpTwf + (size_t)(s * 128 + li) * GD;                 orow = (size_t)s * 128 + li;        ocol = colG;      }
        else          { const int t = 63 - s; xp = xpTwb + (size_t)(t * 128 + li) * GD; orow = (size_t)t * 128 + li;  ocol = HD + colG; }
        isTW = true;
      } else {
        const int li = lr;
        if (dir == 0) { xp = xpTpf + (size_t)(s * 16 + li) * GD;                  orow = (size_t)s * 16 + li;         ocol = colG;      }
        else          { const int t = 63 - s; xp = xpTpb + (size_t)(t * 16 + li) * GD;  orow = (size_t)t * 16 + li;   ocol = HD + colG; }
        isTW = false;
      }
      float rv = sigmoidf_(xp[colG]          + acc[0][p] + bhh[colG]);
      float zv = sigmoidf_(xp[HD + colG]     + acc[1][p] + bhh[HD + colG]);
      float nv = tanhf   (xp[2 * HD + colG]  + rv * (acc[2][p] + bhh[2 * HD + colG]));
      float hp = bf2f(HcHi[(size_t)gr * HD + colG]) + bf2f(HcLo[(size_t)gr * HD + colG]);
      float h = (1.f - zv) * nv + zv * hp;
      ushort_t hh = f2bf(h);
      ushort_t hl = f2bf(h - bf2f(hh));
      Hn[(size_t)gr * HD + colG] = hh;
      Hn[U_HLO + (size_t)gr * HD + colG] = hl;
      if (isTW) { TWhi[orow * DD + ocol] = hh; TWlo[orow * DD + ocol] = hl; }
      else      { TPhi[orow * DD + ocol] = hh; TPlo[orow * DD + ocol] = hl; }
    }
  }
}

// ---------------- attn S + softmax per b ----------------
__global__ __launch_bounds__(256) void attn_s_kernel(
    const ushort_t* __restrict__ TPWhi, const ushort_t* __restrict__ TPWlo,
    const ushort_t* __restrict__ TWhi, const ushort_t* __restrict__ TWlo,
    float* __restrict__ attg)
{
  __shared__ __align__(16) ushort_t Ah[24576];
  __shared__ __align__(16) ushort_t Al[24576];
  __shared__ __align__(16) ushort_t Bs[2][4096];
  __shared__ float Sl[16][132];
  const int b = blockIdx.x;
  const int tid = threadIdx.x, lane = tid & 63, w = tid >> 6;
  const int r = lane & 15, kc = (lane >> 4) << 3;

  {
    const ushort_t* sH = TPWhi + ((size_t)b * 16 + r) * DD + kc;
    const ushort_t* sL = TPWlo + ((size_t)b * 16 + r) * DD + kc;
#pragma unroll
    for (int ii = 0; ii < 12; ++ii) {
      int kb = w * 12 + ii;
      glds16(sH + kb * 32, Ah + kb * 512);
      glds16(sL + kb * 32, Al + kb * 512);
    }
  }
  auto stageB = [&](int buf, const ushort_t* src, int koff) {
#pragma unroll
    for (int ii = 0; ii < 2; ++ii) {
      int nf = w * 2 + ii;
      glds16(src + ((size_t)b * 128 + nf * 16 + r) * DD + koff + kc, Bs[buf] + nf * 512);
    }
  };
  stageB(0, TWhi, 0);
  __syncthreads();

  f32x4 acc[2];
  acc[0] = (f32x4){0.f, 0.f, 0.f, 0.f};
  acc[1] = (f32x4){0.f, 0.f, 0.f, 0.f};
  for (int c = 0; c < 96; ++c) {
    if (c < 95) {
      int nc = c + 1;
      stageB(nc & 1, (nc < 48) ? TWhi : TWlo, (nc % 48) * 32);
    }
    const int kb = c % 48;
    bfrag8 aH = *reinterpret_cast<const bfrag8*>(reinterpret_cast<const char*>(Ah) + kb * 1024 + lane * 16);
    bfrag8 b0 = *reinterpret_cast<const bfrag8*>(reinterpret_cast<const char*>(Bs[c & 1]) + (w * 2 + 0) * 1024 + lane * 16);
    bfrag8 b1 = *reinterpret_cast<const bfrag8*>(reinterpret_cast<const char*>(Bs[c & 1]) + (w * 2 + 1) * 1024 + lane * 16);
    acc[0] = __builtin_amdgcn_mfma_f32_16x16x32_bf16(aH, b0, acc[0], 0, 0, 0);
    acc[1] = __builtin_amdgcn_mfma_f32_16x16x32_bf16(aH, b1, acc[1], 0, 0, 0);
    if (c < 48) {
      bfrag8 aL = *reinterpret_cast<const bfrag8*>(reinterpret_cast<const char*>(Al) + kb * 1024 + lane * 16);
      acc[0] = __builtin_amdgcn_mfma_f32_16x16x32_bf16(aL, b0, acc[0], 0, 0, 0);
      acc[1] = __builtin_amdgcn_mfma_f32_16x16x32_bf16(aL, b1, acc[1], 0, 0, 0);
    }
    __syncthreads();
  }

#pragma unroll
  for (int nfl = 0; nfl < 2; ++nfl) {
    int l = (w * 2 + nfl) * 16 + (lane & 15);
#pragma unroll
    for (int p = 0; p < 4; ++p) Sl[(lane >> 4) * 4 + p][l] = acc[nfl][p];
  }
  __syncthreads();

  const int t = tid >> 4, j = tid & 15;
  float4 v0 = *reinterpret_cast<const float4*>(&Sl[t][j * 8]);
  float4 v1 = *reinterpret_cast<const float4*>(&Sl[t][j * 8 + 4]);
  float m = fmaxf(fmaxf(fmaxf(v0.x, v0.y), fmaxf(v0.z, v0.w)),
                  fmaxf(fmaxf(v1.x, v1.y), fmaxf(v1.z, v1.w)));
#pragma unroll
  for (int mk = 1; mk < 16; mk <<= 1) m = fmaxf(m, __shfl_xor(m, mk));
  float e[8];
  e[0] = expf(v0.x - m); e[1] = expf(v0.y - m); e[2] = expf(v0.z - m); e[3] = expf(v0.w - m);
  e[4] = expf(v1.x - m); e[5] = expf(v1.y - m); e[6] = expf(v1.z - m); e[7] = expf(v1.w - m);
  float ssum = e[0] + e[1] + e[2] + e[3] + e[4] + e[5] + e[6] + e[7];
#pragma unroll
  for (int mk = 1; mk < 16; mk <<= 1) ssum += __shfl_xor(ssum, mk);
  const float inv = 1.f / ssum;
  float* po = attg + (size_t)b * 2048 + t * 128 + j * 8;
  *reinterpret_cast<float4*>(po)     = make_float4(e[0] * inv, e[1] * inv, e[2] * inv, e[3] * inv);
  *reinterpret_cast<float4*>(po + 4) = make_float4(e[4] * inv, e[5] * inv, e[6] * inv, e[7] * inv);
}

// ---------------- r2 ----------------
__global__ __launch_bounds__(256) void r2_kernel(
    const float* __restrict__ attg, const ushort_t* __restrict__ TWhi,
    const ushort_t* __restrict__ TWlo, float* __restrict__ Rr)
{
  __shared__ float al[2048];
  const int b = blockIdx.y;
  const int d = blockIdx.x * 256 + threadIdx.x;
  for (int i = threadIdx.x; i < 2048; i += 256) al[i] = attg[(size_t)b * 2048 + i];
  __syncthreads();
  float racc[16];
#pragma unroll
  for (int t = 0; t < 16; ++t) racc[t] = 0.f;
  for (int l = 0; l < 128; ++l) {
    size_t o = ((size_t)b * 128 + l) * DD + d;
    float tw = bf2f(TWhi[o]) + bf2f(TWlo[o]);
#pragma unroll
    for (int t = 0; t < 16; ++t) racc[t] += al[t * 128 + l] * tw;
  }
#pragma unroll
  for (int t = 0; t < 16; ++t) Rr[((size_t)b * 16 + t) * DD + d] = racc[t];
}

// ---------------- R assembly + head ----------------
__global__ __launch_bounds__(256) void final_kernel(
    const float* __restrict__ Rr, const float* __restrict__ beta,
    const float* __restrict__ detW, const float* __restrict__ detb,
    float* __restrict__ dout)
{
  __shared__ float bet[16];
  __shared__ float red0[256], red1[256];
  const int b = blockIdx.x, tid = threadIdx.x;
  if (tid < 16) bet[tid] = beta[tid];
  __syncthreads();
  const float* rb = Rr + (size_t)b * 16 * DD;
  float* Rout = dout + 128 + (size_t)b * 3072;
  float p0 = 0.f, p1 = 0.f;
  for (int d = tid; d < 3072; d += 256) {
    float v;
    if (d < DD) {
      v = rb[15 * DD + d];
    } else {
      float sum = 0.f;
#pragma unroll
      for (int tt = 0; tt < 15; ++tt) sum += bet[tt] * rb[(size_t)tt * DD + (d - DD)];
      v = sum;
    }
    Rout[d] = v;
    p0 += v * detW[d];
    p1 += v * detW[3072 + d];
  }
  red0[tid] = p0; red1[tid] = p1;
  __syncthreads();
  for (int off = 128; off > 0; off >>= 1) {
    if (tid < off) { red0[tid] += red0[tid + off]; red1[tid] += red1[tid + off]; }
    __syncthreads();
  }
  if (tid == 0) {
    dout[b * 2 + 0] = red0[0] + detb[0];
    dout[b * 2 + 1] = red1[0] + detb[1];
  }
}

// ---------------- launch ----------------
extern "C" void kernel_launch(void* const* d_in, const int* in_sizes, int n_in,
                              void* d_out, int out_size, void* d_ws, size_t ws_size,
                              hipStream_t stream)
{
  (void)in_sizes; (void)n_in; (void)out_size; (void)ws_size;
  const int*   tweet = (const int*)  d_in[0];
  const int*   topic = (const int*)  d_in[1];
  const float* beta  = (const float*)d_in[2];
  const float* emb   = (const float*)d_in[3];
  const float* Wih_f = (const float*)d_in[4];
  const float* Whh_f = (const float*)d_in[5];
  const float* bih_f = (const float*)d_in[6];
  const float* bhh_f = (const float*)d_in[7];
  const float* Wih_b = (const float*)d_in[8];
  const float* Whh_b = (const float*)d_in[9];
  const float* bih_b = (const float*)d_in[10];
  const float* bhh_b = (const float*)d_in[11];
  const float* W_bl  = (const float*)d_in[12];
  const float* det_W = (const float*)d_in[13];
  const float* det_b = (const float*)d_in[14];

  float* ws = (float*)d_ws;
  float* xp_twf = ws + F_XP_TWF;
  float* xp_twb = ws + F_XP_TWB;
  float* xp_tpf = ws + F_XP_TPF;
  float* xp_tpb = ws + F_XP_TPB;
  float* attg   = ws + F_ATT;
  float* Rr     = ws + F_R;
  ushort_t* TPWhi = (ushort_t*)(ws + F_TPWHI);
  ushort_t* TPWlo = (ushort_t*)(ws + F_TPWLO);
  ushort_t* WblTh = (ushort_t*)(ws + F_WBLT_HI);
  ushort_t* WblTl = (ushort_t*)(ws + F_WBLT_LO);
  ushort_t* uB    = (ushort_t*)(ws + F_B);
  ushort_t* uWhh  = (ushort_t*)(ws + F_WHH);
  ushort_t* uH    = (ushort_t*)(ws + F_H);

  // phase 0: zero H pair 0
  zero_kernel<<<dim3(864), dim3(256), 0, stream>>>(ws + F_H, 221184);

  // phase 1: bf16 splits
  gather_split_kernel<<<dim3(6144), dim3(256), 0, stream>>>(tweet, emb, uB + U_XTW_HI, uB + U_XTW_LO, 1572864);
  gather_split_kernel<<<dim3(768),  dim3(256), 0, stream>>>(topic, emb, uB + U_XTP_HI, uB + U_XTP_LO, 196608);
  split_w_kernel<<<dim3(1728), dim3(256), 0, stream>>>(Wih_f, uB + U_WIHF_HI, uB + U_WIHF_LO, 442368);
  split_w_kernel<<<dim3(1728), dim3(256), 0, stream>>>(Wih_b, uB + U_WIHB_HI, uB + U_WIHB_LO, 442368);
  split_w_kernel<<<dim3(1728), dim3(256), 0, stream>>>(Whh_f, uWhh + U_WHHF_HI, uWhh + U_WHHF_LO, 442368);
  split_w_kernel<<<dim3(1728), dim3(256), 0, stream>>>(Whh_b, uWhh + U_WHHB_HI, uWhh + U_WHHB_LO, 442368);

  // phase 2: xp GEMMs
  mfma_gemm_kernel<false><<<dim3(1152), dim3(256), 0, stream>>>(uB + U_XTW_HI, uB + U_XTW_LO, uB + U_WIHF_HI, uB + U_WIHF_LO, bih_f, xp_twf, nullptr, nullptr, HD, GD, 64);
  mfma_gemm_kernel<false><<<dim3(1152), dim3(256), 0, stream>>>(uB + U_XTW_HI, uB + U_XTW_LO, uB + U_WIHB_HI, uB + U_WIHB_LO, bih_b, xp_twb, nullptr, nullptr, HD, GD, 64);
  mfma_gemm_kernel<false><<<dim3(144),  dim3(256), 0, stream>>>(uB + U_XTP_HI, uB + U_XTP_LO, uB + U_WIHF_HI, uB + U_WIHF_LO, bih_f, xp_tpf, nullptr, nullptr, HD, GD, 8);
  mfma_gemm_kernel<false><<<dim3(144),  dim3(256), 0, stream>>>(uB + U_XTP_HI, uB + U_XTP_LO, uB + U_WIHB_HI, uB + U_WIHB_LO, bih_b, xp_tpb, nullptr, nullptr, HD, GD, 8);

  // phase 3: 64 GRU steps (gru3: XCD-pinned Whh)
  for (int s = 0; s < 64; ++s) {
    const ushort_t* Hc = uH + (size_t)(s & 1) * U_HPAIR;
    ushort_t*       Hn = uH + (size_t)((s & 1) ^ 1) * U_HPAIR;
    gru3_kernel<<<dim3(240), dim3(256), 0, stream>>>(
        uWhh + U_WHHF_HI, uWhh + U_WHHF_LO, uWhh + U_WHHB_HI, uWhh + U_WHHB_LO,
        bhh_f, bhh_b, xp_twf, xp_twb, xp_tpf, xp_tpb, Hc, Hn,
        uB + U_TWHI, uB + U_TWLO, uB + U_TPHI, uB + U_TPLO, s);
  }

  // phase 4: attention + head
  transp_split_kernel<<<dim3(48, 48), dim3(256), 0, stream>>>(W_bl, WblTh, WblTl);
  mfma_gemm_kernel<true><<<dim3(96), dim3(256), 0, stream>>>(uB + U_TPHI, uB + U_TPLO, WblTh, WblTl, nullptr, nullptr, TPWhi, TPWlo, DD, DD, 8);
  attn_s_kernel<<<dim3(64), dim3(256), 0, stream>>>(TPWhi, TPWlo, uB + U_TWHI, uB + U_TWLO, attg);
  r2_kernel<<<dim3(6, 64), dim3(256), 0, stream>>>(attg, uB + U_TWHI, uB + U_TWLO, Rr);
  final_kernel<<<dim3(64), dim3(256), 0, stream>>>(Rr, beta, det_W, det_b, (float*)d_out);
}

// Round 6
// 1608.777 us; speedup vs baseline: 1.5021x; 1.1679x over previous
//
#include <hip/hip_runtime.h>
#include <hip/hip_bf16.h>
#include <cstdint>
#include <cstddef>

#define HD 768   // H == H2
#define GD 2304  // 3*H2
#define DD 1536  // 2*H2

typedef __attribute__((ext_vector_type(8))) short bfrag8;  // 8 bf16 (4 VGPRs)
typedef __attribute__((ext_vector_type(4))) float f32x4;   // MFMA acc
typedef unsigned short ushort_t;

// ---------------- workspace layout ----------------
static constexpr size_t F_XP_TWF = 0;                      // 8192*2304
static constexpr size_t F_XP_TWB = 18874368;
static constexpr size_t F_XP_TPF = 37748736;               // 1024*2304
static constexpr size_t F_XP_TPB = 40108032;
// phase-4 overlay inside dead xp_twf region:
static constexpr size_t F_TPWHI  = 0;
static constexpr size_t F_TPWLO  = 786432;
static constexpr size_t F_WBLT_HI = 2000000;
static constexpr size_t F_WBLT_LO = 3200000;
static constexpr size_t F_ATT    = 5000000;
static constexpr size_t F_R      = 6000000;
// region B: phase1-2 = X/Wih splits; phase3+ = TW/TP bf16 pairs
static constexpr size_t F_B      = 42467328;
static constexpr size_t U_XTW_HI  = 0;
static constexpr size_t U_XTW_LO  = 6291456;
static constexpr size_t U_XTP_HI  = 12582912;
static constexpr size_t U_XTP_LO  = 13369344;
static constexpr size_t U_WIHF_HI = 14155776;
static constexpr size_t U_WIHF_LO = 15925248;
static constexpr size_t U_WIHB_HI = 17694720;
static constexpr size_t U_WIHB_LO = 19464192;
static constexpr size_t U_TWHI   = 0;
static constexpr size_t U_TWLO   = 12582912;
static constexpr size_t U_TPHI   = 25165824;
static constexpr size_t U_TPLO   = 26738688;
// region Whh splits
static constexpr size_t F_WHH    = F_B + 14155776;
static constexpr size_t U_WHHF_HI = 0;
static constexpr size_t U_WHHF_LO = 1769472;
static constexpr size_t U_WHHB_HI = 3538944;
static constexpr size_t U_WHHB_LO = 5308416;
// H state: bf16 hi/lo ping-pong pairs
static constexpr size_t F_H      = F_WHH + 3538944;
static constexpr size_t U_HPAIR  = 442368;
static constexpr size_t U_HLO    = 221184;

__device__ __forceinline__ float sigmoidf_(float x) { return 1.f / (1.f + expf(-x)); }
__device__ __forceinline__ ushort_t f2bf(float f) {
  unsigned int u = __builtin_bit_cast(unsigned int, f);
  unsigned int r = (u + 0x7fffu + ((u >> 16) & 1u)) >> 16;
  return (ushort_t)r;
}
__device__ __forceinline__ float bf2f(ushort_t h) {
  unsigned int u = ((unsigned int)h) << 16;
  return __builtin_bit_cast(float, u);
}
__device__ __forceinline__ void glds16(const ushort_t* src, ushort_t* ldsDst) {
  __builtin_amdgcn_global_load_lds((const void*)src, (void*)ldsDst, 16, 0, 0);
}

// ---------------- zero-init ----------------
__global__ void zero_kernel(float* __restrict__ p, int n) {
  int i = blockIdx.x * 256 + threadIdx.x;
  if (i < n) p[i] = 0.f;
}

// ---------------- gather + bf16 hi/lo split ----------------
__global__ __launch_bounds__(256) void gather_split_kernel(
    const int* __restrict__ ids, const float* __restrict__ emb,
    ushort_t* __restrict__ hi, ushort_t* __restrict__ lo, int total4)
{
  int i = blockIdx.x * 256 + threadIdx.x;
  if (i >= total4) return;
  int r = i / 192;
  int c = (i - r * 192) * 4;
  const float4 v = *reinterpret_cast<const float4*>(emb + (size_t)ids[r] * HD + c);
  float vv[4] = {v.x, v.y, v.z, v.w};
  ushort_t h[4], l[4];
#pragma unroll
  for (int e = 0; e < 4; ++e) { h[e] = f2bf(vv[e]); l[e] = f2bf(vv[e] - bf2f(h[e])); }
  size_t base = (size_t)i * 4;
  *reinterpret_cast<uint2*>(hi + base) = make_uint2((unsigned)h[0] | ((unsigned)h[1] << 16), (unsigned)h[2] | ((unsigned)h[3] << 16));
  *reinterpret_cast<uint2*>(lo + base) = make_uint2((unsigned)l[0] | ((unsigned)l[1] << 16), (unsigned)l[2] | ((unsigned)l[3] << 16));
}

__global__ __launch_bounds__(256) void split_w_kernel(
    const float* __restrict__ src, ushort_t* __restrict__ hi,
    ushort_t* __restrict__ lo, int total4)
{
  int i = blockIdx.x * 256 + threadIdx.x;
  if (i >= total4) return;
  const float4 v = *reinterpret_cast<const float4*>(src + (size_t)i * 4);
  float vv[4] = {v.x, v.y, v.z, v.w};
  ushort_t h[4], l[4];
#pragma unroll
  for (int e = 0; e < 4; ++e) { h[e] = f2bf(vv[e]); l[e] = f2bf(vv[e] - bf2f(h[e])); }
  size_t base = (size_t)i * 4;
  *reinterpret_cast<uint2*>(hi + base) = make_uint2((unsigned)h[0] | ((unsigned)h[1] << 16), (unsigned)h[2] | ((unsigned)h[3] << 16));
  *reinterpret_cast<uint2*>(lo + base) = make_uint2((unsigned)l[0] | ((unsigned)l[1] << 16), (unsigned)l[2] | ((unsigned)l[3] << 16));
}

// ---------------- W_bl transpose + split ----------------
__global__ __launch_bounds__(256) void transp_split_kernel(
    const float* __restrict__ src, ushort_t* __restrict__ hi, ushort_t* __restrict__ lo)
{
  __shared__ float t[32][33];
  const int bx = blockIdx.x, by = blockIdx.y, tid = threadIdx.x;
  const int r = tid >> 3, c4 = (tid & 7) * 4;
  const float4 v = *reinterpret_cast<const float4*>(src + (size_t)(by * 32 + r) * DD + bx * 32 + c4);
  t[r][c4 + 0] = v.x; t[r][c4 + 1] = v.y; t[r][c4 + 2] = v.z; t[r][c4 + 3] = v.w;
  __syncthreads();
  ushort_t h[4], l[4];
#pragma unroll
  for (int j = 0; j < 4; ++j) {
    float o = t[c4 + j][r];
    h[j] = f2bf(o); l[j] = f2bf(o - bf2f(h[j]));
  }
  size_t ob = (size_t)(bx * 32 + r) * DD + by * 32 + c4;
  *reinterpret_cast<uint2*>(hi + ob) = make_uint2((unsigned)h[0] | ((unsigned)h[1] << 16), (unsigned)h[2] | ((unsigned)h[3] << 16));
  *reinterpret_cast<uint2*>(lo + ob) = make_uint2((unsigned)l[0] | ((unsigned)l[1] << 16), (unsigned)l[2] | ((unsigned)l[3] << 16));
}

// ---------------- generalized bf16x3 MFMA GEMM ----------------
// A-panel-sticky XCD mapping: each XCD owns mgc/8 A-panels (L2-resident),
// streams B once. mg = xcd*(mgc/8) + off%(mgc/8); cg = off/(mgc/8).
template<bool SPLIT_OUT>
__global__ __launch_bounds__(256, 3) void mfma_gemm_kernel(
    const ushort_t* __restrict__ Ahi, const ushort_t* __restrict__ Alo,
    const ushort_t* __restrict__ Bhi, const ushort_t* __restrict__ Blo,
    const float* __restrict__ bias, float* __restrict__ outF,
    ushort_t* __restrict__ outHi, ushort_t* __restrict__ outLo,
    const int K, const int N, const int mgc)
{
  __shared__ __align__(16) ushort_t sm[6][4096];
  const int b = blockIdx.x;
  const int xcdq = b & 7, off = b >> 3;
  const int mpx = mgc >> 3;                         // A-panels per XCD (>=1)
  const int mg = xcdq * mpx + (off % mpx);
  const int cg = off / mpx;
  const size_t mBase = (size_t)mg * 128, nBase = (size_t)cg * 128;
  const int tid = threadIdx.x, lane = tid & 63, w = tid >> 6;
  const int wr = w >> 1, wc = w & 1;
  const int KB = K >> 5;

  const ushort_t* Ah = Ahi + mBase * K;
  const ushort_t* Al = Alo + mBase * K;
  const ushort_t* Bh = Bhi + nBase * K;
  const ushort_t* Bl = Blo + nBase * K;

  f32x4 acc[4][4];
#pragma unroll
  for (int i = 0; i < 4; ++i)
#pragma unroll
    for (int j = 0; j < 4; ++j) acc[i][j] = (f32x4){0.f, 0.f, 0.f, 0.f};

  auto stageF = [&](int buf, int koff) {
    ushort_t* Bt  = sm[buf * 3 + 0];
    ushort_t* At0 = sm[buf * 3 + 1];
    ushort_t* At1 = sm[buf * 3 + 2];
#pragma unroll
    for (int ii = 0; ii < 2; ++ii) {
      int i16 = w * 2 + ii;
      int row = i16 * 16 + (lane >> 2), c16 = lane & 3;
      size_t so = (size_t)row * K + (size_t)(koff + ((c16 ^ (row & 3)) << 3));
      glds16(Bh + so, Bt + i16 * 512);
      glds16(Ah + so, At0 + i16 * 512);
      glds16(Al + so, At1 + i16 * 512);
    }
  };
  auto stageP = [&](int buf, int koff) {
    ushort_t* Bt  = sm[buf * 3 + 0];
    ushort_t* At0 = sm[buf * 3 + 1];
#pragma unroll
    for (int ii = 0; ii < 2; ++ii) {
      int i16 = w * 2 + ii;
      int row = i16 * 16 + (lane >> 2), c16 = lane & 3;
      size_t so = (size_t)row * K + (size_t)(koff + ((c16 ^ (row & 3)) << 3));
      glds16(Bl + so, Bt + i16 * 512);
      glds16(Ah + so, At0 + i16 * 512);
    }
  };
  const int kch = (lane >> 4) << 4;

  auto compute = [&](int buf, bool both) {
    const char* Bt  = reinterpret_cast<const char*>(sm[buf * 3 + 0]);
    const char* At0 = reinterpret_cast<const char*>(sm[buf * 3 + 1]);
    const char* At1 = reinterpret_cast<const char*>(sm[buf * 3 + 2]);
    bfrag8 bF[4], aF[4];
#pragma unroll
    for (int j = 0; j < 4; ++j) {
      int row = wc * 64 + j * 16 + (lane & 15);
      bF[j] = *reinterpret_cast<const bfrag8*>(Bt + row * 64 + (kch ^ ((row & 3) << 4)));
    }
#pragma unroll
    for (int i = 0; i < 4; ++i) {
      int row = wr * 64 + i * 16 + (lane & 15);
      aF[i] = *reinterpret_cast<const bfrag8*>(At0 + row * 64 + (kch ^ ((row & 3) << 4)));
    }
#pragma unroll
    for (int i = 0; i < 4; ++i)
#pragma unroll
      for (int j = 0; j < 4; ++j)
        acc[i][j] = __builtin_amdgcn_mfma_f32_16x16x32_bf16(aF[i], bF[j], acc[i][j], 0, 0, 0);
    if (both) {
#pragma unroll
      for (int i = 0; i < 4; ++i) {
        int row = wr * 64 + i * 16 + (lane & 15);
        aF[i] = *reinterpret_cast<const bfrag8*>(At1 + row * 64 + (kch ^ ((row & 3) << 4)));
      }
#pragma unroll
      for (int i = 0; i < 4; ++i)
#pragma unroll
        for (int j = 0; j < 4; ++j)
          acc[i][j] = __builtin_amdgcn_mfma_f32_16x16x32_bf16(aF[i], bF[j], acc[i][j], 0, 0, 0);
    }
  };

  stageF(0, 0);
  __syncthreads();
  for (int kb = 0; kb < KB; ++kb) {
    if (kb < KB - 1) stageF((kb + 1) & 1, (kb + 1) * 32);
    else             stageP(0, 0);
    compute(kb & 1, true);
    __syncthreads();
  }
  for (int kb = 0; kb < KB; ++kb) {
    if (kb < KB - 1) stageP((kb + 1) & 1, (kb + 1) * 32);
    compute(kb & 1, false);
    __syncthreads();
  }

#pragma unroll
  for (int i = 0; i < 4; ++i)
#pragma unroll
    for (int j = 0; j < 4; ++j) {
      int col = (int)nBase + wc * 64 + j * 16 + (lane & 15);
#pragma unroll
      for (int p = 0; p < 4; ++p) {
        size_t row = mBase + wr * 64 + i * 16 + ((lane >> 4) << 2) + p;
        if constexpr (SPLIT_OUT) {
          float v = acc[i][j][p];
          ushort_t hh = f2bf(v);
          outHi[row * N + col] = hh;
          outLo[row * N + col] = f2bf(v - bf2f(hh));
        } else {
          outF[row * N + col] = acc[i][j][p] + bias[col];
        }
      }
    }
}

// ---------------- GRU step v4: XCD-pinned Whh + 4-deep counted-vmcnt pipeline ----------------
// Grid 240 (= 8 XCD x 30). Same decomposition as v3. LDS: 4 staging bufs x 16
// frag-slots (1KB) = 64 KB. Every wave issues EXACTLY 4 glds16 per stage
// (topic blocks duplicate A loads) so vmcnt counting is uniform.
// Pipeline: prologue stages chunks 0-2; iter kb: vmcnt(8) -> s_barrier ->
// compute(kb&3) -> stage(kb+3). Never drains vmcnt to 0 mid-loop (T3/T4).
__global__ __launch_bounds__(256) void gru4_kernel(
    const ushort_t* __restrict__ WfHi, const ushort_t* __restrict__ WfLo,
    const ushort_t* __restrict__ WbHi, const ushort_t* __restrict__ WbLo,
    const float* __restrict__ bhhF, const float* __restrict__ bhhB,
    const float* __restrict__ xpTwf, const float* __restrict__ xpTwb,
    const float* __restrict__ xpTpf, const float* __restrict__ xpTpb,
    const ushort_t* __restrict__ Hc, ushort_t* __restrict__ Hn,
    ushort_t* __restrict__ TWhi, ushort_t* __restrict__ TWlo,
    ushort_t* __restrict__ TPhi, ushort_t* __restrict__ TPlo, const int s)
{
  __shared__ __align__(16) ushort_t sm[4][16][512];
  const int bid = blockIdx.x;
  const int xcd = bid & 7, kk = bid >> 3;          // kk 0..29
  const bool isTweet = (kk < 24);
  const int sl = isTweet ? (kk >> 2) : (kk - 24);  // 0..5
  const int rg = isTweet ? (kk & 3) : 0;
  const int slice = xcd * 6 + sl;                  // 0..47
  const int cg = slice >> 1, dir = slice & 1;
  const int j0 = cg * 32;
  const int Mfrags = isTweet ? 2 : 1;
  const int baseR = dir * 144 + (isTweet ? rg * 32 : 128);
  const ushort_t* __restrict__ Whi = dir ? WbHi : WfHi;
  const ushort_t* __restrict__ Wlo = dir ? WbLo : WfLo;
  const float* __restrict__ bhh = dir ? bhhB : bhhF;
  const int tid = threadIdx.x, lane = tid & 63, w = tid >> 6;
  const ushort_t* HcHi = Hc;
  const ushort_t* HcLo = Hc + U_HLO;

  const int mf = isTweet ? (w & 1) : 0;
  const int ch = isTweet ? (w >> 1) : w;
  const bool doCompute = isTweet || (w < 2);

  // stage: wave w stages slots 4w..4w+3 of chunk kb (always 4 loads/wave)
  auto stage = [&](int buf, int kb) {
    const int r16 = lane & 15, k8 = (lane >> 4) << 3;
#pragma unroll
    for (int i = 0; i < 4; ++i) {
      const int slot = w * 4 + i;
      const ushort_t* src;
      if (slot < 4) {
        const int m = slot >> 1, p = slot & 1;
        const int mm = (m < Mfrags) ? m : 0;       // topic: duplicate slot 0/1
        src = (p ? HcLo : HcHi) + (size_t)(baseR + mm * 16 + r16) * HD + kb * 32 + k8;
      } else {
        const int idx = slot - 4;                  // (g*2+c2)*2+p
        const int p = idx & 1, c2 = (idx >> 1) & 1, g = idx >> 2;
        const ushort_t* W = p ? Wlo : Whi;
        src = W + (size_t)(g * HD + j0 + c2 * 16 + r16) * HD + kb * 32 + k8;
      }
      glds16(src, &sm[buf][slot][0]);
    }
  };

  f32x4 acc[3];
#pragma unroll
  for (int g = 0; g < 3; ++g) acc[g] = (f32x4){0.f, 0.f, 0.f, 0.f};

  auto computeT = [&](int buf) {
    if (!doCompute) return;
    const char* base = reinterpret_cast<const char*>(&sm[buf][0][0]);
    const int aoff = mf * 2;
    bfrag8 Ah = *reinterpret_cast<const bfrag8*>(base + (aoff + 0) * 1024 + lane * 16);
    bfrag8 Al = *reinterpret_cast<const bfrag8*>(base + (aoff + 1) * 1024 + lane * 16);
#pragma unroll
    for (int g = 0; g < 3; ++g) {
      const int bidx = 4 + (g * 2 + ch) * 2;
      bfrag8 Bh = *reinterpret_cast<const bfrag8*>(base + (bidx + 0) * 1024 + lane * 16);
      bfrag8 Bl = *reinterpret_cast<const bfrag8*>(base + (bidx + 1) * 1024 + lane * 16);
      acc[g] = __builtin_amdgcn_mfma_f32_16x16x32_bf16(Ah, Bh, acc[g], 0, 0, 0);
      acc[g] = __builtin_amdgcn_mfma_f32_16x16x32_bf16(Al, Bh, acc[g], 0, 0, 0);
      acc[g] = __builtin_amdgcn_mfma_f32_16x16x32_bf16(Ah, Bl, acc[g], 0, 0, 0);
    }
  };

  // prologue: 3 stages in flight
  stage(0, 0); stage(1, 1); stage(2, 2);
#pragma unroll
  for (int kb = 0; kb < 24; ++kb) {
    if (kb < 22)       asm volatile("s_waitcnt vmcnt(8)" ::: "memory");
    else if (kb == 22) asm volatile("s_waitcnt vmcnt(4)" ::: "memory");
    else               asm volatile("s_waitcnt vmcnt(0)" ::: "memory");
    __builtin_amdgcn_s_barrier();
    __builtin_amdgcn_sched_barrier(0);
    computeT(kb & 3);
    if (kb < 21) stage((kb + 3) & 3, kb + 3);
  }

  // epilogue
  if (doCompute) {
    const int colG = j0 + ch * 16 + (lane & 15);   // 0..767
#pragma unroll
    for (int p = 0; p < 4; ++p) {
      const int lr = mf * 16 + ((lane >> 4) << 2) + p;
      const int gr = baseR + lr;
      const float* xp; size_t orow; int ocol; bool isTW;
      if (isTweet) {
        const int li = rg * 32 + lr;
        if (dir == 0) { xp = xpTwf + (size_t)(s * 128 + li) * GD;                 orow = (size_t)s * 128 + li;        ocol = colG;      }
        else          { const int t = 63 - s; xp = xpTwb + (size_t)(t * 128 + li) * GD; orow = (size_t)t * 128 + li;  ocol = HD + colG; }
        isTW = true;
      } else {
        const int li = lr;
        if (dir == 0) { xp = xpTpf + (size_t)(s * 16 + li) * GD;                  orow = (size_t)s * 16 + li;         ocol = colG;      }
        else          { const int t = 63 - s; xp = xpTpb + (size_t)(t * 16 + li) * GD;  orow = (size_t)t * 16 + li;   ocol = HD + colG; }
        isTW = false;
      }
      float rv = sigmoidf_(xp[colG]          + acc[0][p] + bhh[colG]);
      float zv = sigmoidf_(xp[HD + colG]     + acc[1][p] + bhh[HD + colG]);
      float nv = tanhf   (xp[2 * HD + colG]  + rv * (acc[2][p] + bhh[2 * HD + colG]));
      float hp = bf2f(HcHi[(size_t)gr * HD + colG]) + bf2f(HcLo[(size_t)gr * HD + colG]);
      float h = (1.f - zv) * nv + zv * hp;
      ushort_t hh = f2bf(h);
      ushort_t hl = f2bf(h - bf2f(hh));
      Hn[(size_t)gr * HD + colG] = hh;
      Hn[U_HLO + (size_t)gr * HD + colG] = hl;
      if (isTW) { TWhi[orow * DD + ocol] = hh; TWlo[orow * DD + ocol] = hl; }
      else      { TPhi[orow * DD + ocol] = hh; TPlo[orow * DD + ocol] = hl; }
    }
  }
}

// ---------------- attn S + softmax per b ----------------
__global__ __launch_bounds__(256) void attn_s_kernel(
    const ushort_t* __restrict__ TPWhi, const ushort_t* __restrict__ TPWlo,
    const ushort_t* __restrict__ TWhi, const ushort_t* __restrict__ TWlo,
    float* __restrict__ attg)
{
  __shared__ __align__(16) ushort_t Ah[24576];
  __shared__ __align__(16) ushort_t Al[24576];
  __shared__ __align__(16) ushort_t Bs[2][4096];
  __shared__ float Sl[16][132];
  const int b = blockIdx.x;
  const int tid = threadIdx.x, lane = tid & 63, w = tid >> 6;
  const int r = lane & 15, kc = (lane >> 4) << 3;

  {
    const ushort_t* sH = TPWhi + ((size_t)b * 16 + r) * DD + kc;
    const ushort_t* sL = TPWlo + ((size_t)b * 16 + r) * DD + kc;
#pragma unroll
    for (int ii = 0; ii < 12; ++ii) {
      int kb = w * 12 + ii;
      glds16(sH + kb * 32, Ah + kb * 512);
      glds16(sL + kb * 32, Al + kb * 512);
    }
  }
  auto stageB = [&](int buf, const ushort_t* src, int koff) {
#pragma unroll
    for (int ii = 0; ii < 2; ++ii) {
      int nf = w * 2 + ii;
      glds16(src + ((size_t)b * 128 + nf * 16 + r) * DD + koff + kc, Bs[buf] + nf * 512);
    }
  };
  stageB(0, TWhi, 0);
  __syncthreads();

  f32x4 acc[2];
  acc[0] = (f32x4){0.f, 0.f, 0.f, 0.f};
  acc[1] = (f32x4){0.f, 0.f, 0.f, 0.f};
  for (int c = 0; c < 96; ++c) {
    if (c < 95) {
      int nc = c + 1;
      stageB(nc & 1, (nc < 48) ? TWhi : TWlo, (nc % 48) * 32);
    }
    const int kb = c % 48;
    bfrag8 aH = *reinterpret_cast<const bfrag8*>(reinterpret_cast<const char*>(Ah) + kb * 1024 + lane * 16);
    bfrag8 b0 = *reinterpret_cast<const bfrag8*>(reinterpret_cast<const char*>(Bs[c & 1]) + (w * 2 + 0) * 1024 + lane * 16);
    bfrag8 b1 = *reinterpret_cast<const bfrag8*>(reinterpret_cast<const char*>(Bs[c & 1]) + (w * 2 + 1) * 1024 + lane * 16);
    acc[0] = __builtin_amdgcn_mfma_f32_16x16x32_bf16(aH, b0, acc[0], 0, 0, 0);
    acc[1] = __builtin_amdgcn_mfma_f32_16x16x32_bf16(aH, b1, acc[1], 0, 0, 0);
    if (c < 48) {
      bfrag8 aL = *reinterpret_cast<const bfrag8*>(reinterpret_cast<const char*>(Al) + kb * 1024 + lane * 16);
      acc[0] = __builtin_amdgcn_mfma_f32_16x16x32_bf16(aL, b0, acc[0], 0, 0, 0);
      acc[1] = __builtin_amdgcn_mfma_f32_16x16x32_bf16(aL, b1, acc[1], 0, 0, 0);
    }
    __syncthreads();
  }

#pragma unroll
  for (int nfl = 0; nfl < 2; ++nfl) {
    int l = (w * 2 + nfl) * 16 + (lane & 15);
#pragma unroll
    for (int p = 0; p < 4; ++p) Sl[(lane >> 4) * 4 + p][l] = acc[nfl][p];
  }
  __syncthreads();

  const int t = tid >> 4, j = tid & 15;
  float4 v0 = *reinterpret_cast<const float4*>(&Sl[t][j * 8]);
  float4 v1 = *reinterpret_cast<const float4*>(&Sl[t][j * 8 + 4]);
  float m = fmaxf(fmaxf(fmaxf(v0.x, v0.y), fmaxf(v0.z, v0.w)),
                  fmaxf(fmaxf(v1.x, v1.y), fmaxf(v1.z, v1.w)));
#pragma unroll
  for (int mk = 1; mk < 16; mk <<= 1) m = fmaxf(m, __shfl_xor(m, mk));
  float e[8];
  e[0] = expf(v0.x - m); e[1] = expf(v0.y - m); e[2] = expf(v0.z - m); e[3] = expf(v0.w - m);
  e[4] = expf(v1.x - m); e[5] = expf(v1.y - m); e[6] = expf(v1.z - m); e[7] = expf(v1.w - m);
  float ssum = e[0] + e[1] + e[2] + e[3] + e[4] + e[5] + e[6] + e[7];
#pragma unroll
  for (int mk = 1; mk < 16; mk <<= 1) ssum += __shfl_xor(ssum, mk);
  const float inv = 1.f / ssum;
  float* po = attg + (size_t)b * 2048 + t * 128 + j * 8;
  *reinterpret_cast<float4*>(po)     = make_float4(e[0] * inv, e[1] * inv, e[2] * inv, e[3] * inv);
  *reinterpret_cast<float4*>(po + 4) = make_float4(e[4] * inv, e[5] * inv, e[6] * inv, e[7] * inv);
}

// ---------------- r2 ----------------
__global__ __launch_bounds__(256) void r2_kernel(
    const float* __restrict__ attg, const ushort_t* __restrict__ TWhi,
    const ushort_t* __restrict__ TWlo, float* __restrict__ Rr)
{
  __shared__ float al[2048];
  const int b = blockIdx.y;
  const int d = blockIdx.x * 256 + threadIdx.x;
  for (int i = threadIdx.x; i < 2048; i += 256) al[i] = attg[(size_t)b * 2048 + i];
  __syncthreads();
  float racc[16];
#pragma unroll
  for (int t = 0; t < 16; ++t) racc[t] = 0.f;
  for (int l = 0; l < 128; ++l) {
    size_t o = ((size_t)b * 128 + l) * DD + d;
    float tw = bf2f(TWhi[o]) + bf2f(TWlo[o]);
#pragma unroll
    for (int t = 0; t < 16; ++t) racc[t] += al[t * 128 + l] * tw;
  }
#pragma unroll
  for (int t = 0; t < 16; ++t) Rr[((size_t)b * 16 + t) * DD + d] = racc[t];
}

// ---------------- R assembly + head ----------------
__global__ __launch_bounds__(256) void final_kernel(
    const float* __restrict__ Rr, const float* __restrict__ beta,
    const float* __restrict__ detW, const float* __restrict__ detb,
    float* __restrict__ dout)
{
  __shared__ float bet[16];
  __shared__ float red0[256], red1[256];
  const int b = blockIdx.x, tid = threadIdx.x;
  if (tid < 16) bet[tid] = beta[tid];
  __syncthreads();
  const float* rb = Rr + (size_t)b * 16 * DD;
  float* Rout = dout + 128 + (size_t)b * 3072;
  float p0 = 0.f, p1 = 0.f;
  for (int d = tid; d < 3072; d += 256) {
    float v;
    if (d < DD) {
      v = rb[15 * DD + d];
    } else {
      float sum = 0.f;
#pragma unroll
      for (int tt = 0; tt < 15; ++tt) sum += bet[tt] * rb[(size_t)tt * DD + (d - DD)];
      v = sum;
    }
    Rout[d] = v;
    p0 += v * detW[d];
    p1 += v * detW[3072 + d];
  }
  red0[tid] = p0; red1[tid] = p1;
  __syncthreads();
  for (int off = 128; off > 0; off >>= 1) {
    if (tid < off) { red0[tid] += red0[tid + off]; red1[tid] += red1[tid + off]; }
    __syncthreads();
  }
  if (tid == 0) {
    dout[b * 2 + 0] = red0[0] + detb[0];
    dout[b * 2 + 1] = red1[0] + detb[1];
  }
}

// ---------------- launch ----------------
extern "C" void kernel_launch(void* const* d_in, const int* in_sizes, int n_in,
                              void* d_out, int out_size, void* d_ws, size_t ws_size,
                              hipStream_t stream)
{
  (void)in_sizes; (void)n_in; (void)out_size; (void)ws_size;
  const int*   tweet = (const int*)  d_in[0];
  const int*   topic = (const int*)  d_in[1];
  const float* beta  = (const float*)d_in[2];
  const float* emb   = (const float*)d_in[3];
  const float* Wih_f = (const float*)d_in[4];
  const float* Whh_f = (const float*)d_in[5];
  const float* bih_f = (const float*)d_in[6];
  const float* bhh_f = (const float*)d_in[7];
  const float* Wih_b = (const float*)d_in[8];
  const float* Whh_b = (const float*)d_in[9];
  const float* bih_b = (const float*)d_in[10];
  const float* bhh_b = (const float*)d_in[11];
  const float* W_bl  = (const float*)d_in[12];
  const float* det_W = (const float*)d_in[13];
  const float* det_b = (const float*)d_in[14];

  float* ws = (float*)d_ws;
  float* xp_twf = ws + F_XP_TWF;
  float* xp_twb = ws + F_XP_TWB;
  float* xp_tpf = ws + F_XP_TPF;
  float* xp_tpb = ws + F_XP_TPB;
  float* attg   = ws + F_ATT;
  float* Rr     = ws + F_R;
  ushort_t* TPWhi = (ushort_t*)(ws + F_TPWHI);
  ushort_t* TPWlo = (ushort_t*)(ws + F_TPWLO);
  ushort_t* WblTh = (ushort_t*)(ws + F_WBLT_HI);
  ushort_t* WblTl = (ushort_t*)(ws + F_WBLT_LO);
  ushort_t* uB    = (ushort_t*)(ws + F_B);
  ushort_t* uWhh  = (ushort_t*)(ws + F_WHH);
  ushort_t* uH    = (ushort_t*)(ws + F_H);

  // phase 0: zero H pair 0
  zero_kernel<<<dim3(864), dim3(256), 0, stream>>>(ws + F_H, 221184);

  // phase 1: bf16 splits
  gather_split_kernel<<<dim3(6144), dim3(256), 0, stream>>>(tweet, emb, uB + U_XTW_HI, uB + U_XTW_LO, 1572864);
  gather_split_kernel<<<dim3(768),  dim3(256), 0, stream>>>(topic, emb, uB + U_XTP_HI, uB + U_XTP_LO, 196608);
  split_w_kernel<<<dim3(1728), dim3(256), 0, stream>>>(Wih_f, uB + U_WIHF_HI, uB + U_WIHF_LO, 442368);
  split_w_kernel<<<dim3(1728), dim3(256), 0, stream>>>(Wih_b, uB + U_WIHB_HI, uB + U_WIHB_LO, 442368);
  split_w_kernel<<<dim3(1728), dim3(256), 0, stream>>>(Whh_f, uWhh + U_WHHF_HI, uWhh + U_WHHF_LO, 442368);
  split_w_kernel<<<dim3(1728), dim3(256), 0, stream>>>(Whh_b, uWhh + U_WHHB_HI, uWhh + U_WHHB_LO, 442368);

  // phase 2: xp GEMMs (A-panel-sticky XCD mapping)
  mfma_gemm_kernel<false><<<dim3(1152), dim3(256), 0, stream>>>(uB + U_XTW_HI, uB + U_XTW_LO, uB + U_WIHF_HI, uB + U_WIHF_LO, bih_f, xp_twf, nullptr, nullptr, HD, GD, 64);
  mfma_gemm_kernel<false><<<dim3(1152), dim3(256), 0, stream>>>(uB + U_XTW_HI, uB + U_XTW_LO, uB + U_WIHB_HI, uB + U_WIHB_LO, bih_b, xp_twb, nullptr, nullptr, HD, GD, 64);
  mfma_gemm_kernel<false><<<dim3(144),  dim3(256), 0, stream>>>(uB + U_XTP_HI, uB + U_XTP_LO, uB + U_WIHF_HI, uB + U_WIHF_LO, bih_f, xp_tpf, nullptr, nullptr, HD, GD, 8);
  mfma_gemm_kernel<false><<<dim3(144),  dim3(256), 0, stream>>>(uB + U_XTP_HI, uB + U_XTP_LO, uB + U_WIHB_HI, uB + U_WIHB_LO, bih_b, xp_tpb, nullptr, nullptr, HD, GD, 8);

  // phase 3: 64 GRU steps (gru4: pipelined)
  for (int s = 0; s < 64; ++s) {
    const ushort_t* Hc = uH + (size_t)(s & 1) * U_HPAIR;
    ushort_t*       Hn = uH + (size_t)((s & 1) ^ 1) * U_HPAIR;
    gru4_kernel<<<dim3(240), dim3(256), 0, stream>>>(
        uWhh + U_WHHF_HI, uWhh + U_WHHF_LO, uWhh + U_WHHB_HI, uWhh + U_WHHB_LO,
        bhh_f, bhh_b, xp_twf, xp_twb, xp_tpf, xp_tpb, Hc, Hn,
        uB + U_TWHI, uB + U_TWLO, uB + U_TPHI, uB + U_TPLO, s);
  }

  // phase 4: attention + head
  transp_split_kernel<<<dim3(48, 48), dim3(256), 0, stream>>>(W_bl, WblTh, WblTl);
  mfma_gemm_kernel<true><<<dim3(96), dim3(256), 0, stream>>>(uB + U_TPHI, uB + U_TPLO, WblTh, WblTl, nullptr, nullptr, TPWhi, TPWlo, DD, DD, 8);
  attn_s_kernel<<<dim3(64), dim3(256), 0, stream>>>(TPWhi, TPWlo, uB + U_TWHI, uB + U_TWLO, attg);
  r2_kernel<<<dim3(6, 64), dim3(256), 0, stream>>>(attg, uB + U_TWHI, uB + U_TWLO, Rr);
  final_kernel<<<dim3(64), dim3(256), 0, stream>>>(Rr, beta, det_W, det_b, (float*)d_out);
}